// Round 1
// baseline (1116.180 us; speedup 1.0000x reference)
//
#include <hip/hip_runtime.h>
#include <math.h>

#define B_    8
#define DIM_  384
#define HEADS_ 8
#define D_    48
#define DH_   24
#define D2_   32
#define HW_   4096
#define IMG   64

// ---------------- reduction helpers ----------------
__device__ __forceinline__ float wred_sum(float v){
#pragma unroll
  for (int m = 32; m; m >>= 1) v += __shfl_xor(v, m);
  return v;
}
__device__ __forceinline__ float wred_max(float v){
#pragma unroll
  for (int m = 32; m; m >>= 1) v = fmaxf(v, __shfl_xor(v, m));
  return v;
}
__device__ __forceinline__ float wred_min(float v){
#pragma unroll
  for (int m = 32; m; m >>= 1) v = fminf(v, __shfl_xor(v, m));
  return v;
}

// block-wide reduce with broadcast; safe to call repeatedly with same lds
template<int OP>  // 0=sum 1=max 2=min
__device__ __forceinline__ float block_red(float v, float* lds){
  if (OP == 0) v = wred_sum(v);
  else if (OP == 1) v = wred_max(v);
  else v = wred_min(v);
  const int lane = threadIdx.x & 63;
  const int wid  = threadIdx.x >> 6;
  __syncthreads();
  if (lane == 0) lds[wid] = v;
  __syncthreads();
  const int nw = blockDim.x >> 6;
  float r = lds[0];
  for (int i = 1; i < nw; ++i){
    float o = lds[i];
    if (OP == 0) r += o; else if (OP == 1) r = fmaxf(r, o); else r = fminf(r, o);
  }
  return r;
}

// depthwise 3x3, SAME zero padding, on a 64x64 fp32 plane
__device__ __forceinline__ float dw3x3(const float* __restrict__ plane,
                                       const float* w9, int y, int x){
  float s = 0.f;
#pragma unroll
  for (int ky = 0; ky < 3; ++ky){
    const int yy = y + ky - 1;
    const bool yok = (unsigned)yy < (unsigned)IMG;
    const float* row = plane + yy * IMG;
#pragma unroll
    for (int kx = 0; kx < 3; ++kx){
      const int xx = x + kx - 1;
      if (yok && ((unsigned)xx < (unsigned)IMG))
        s = fmaf(row[xx], w9[ky*3+kx], s);
    }
  }
  return s;
}

// ---------------- K0: qkv = w_qkv @ x  (per-b GEMM 1152x384x4096) ----------------
__global__ __launch_bounds__(256)
void k_conv1x1(const float* __restrict__ x, const float* __restrict__ w,
               float* __restrict__ y){
  const int b  = blockIdx.z;
  const int o0 = blockIdx.y * 64;
  const int n0 = blockIdx.x * 64;
  __shared__ float Wt[64][17];
  __shared__ float Xt[16][64];
  const int t  = threadIdx.x;
  const int tx = t & 15, ty = t >> 4;
  const float* xb = x + (size_t)b * DIM_ * HW_;
  float acc[4][4] = {{0.f,0.f,0.f,0.f},{0.f,0.f,0.f,0.f},{0.f,0.f,0.f,0.f},{0.f,0.f,0.f,0.f}};
  for (int c0 = 0; c0 < DIM_; c0 += 16){
    {
      const int row = t >> 2, q = (t & 3) << 2;
      float4 wv = *reinterpret_cast<const float4*>(w + (size_t)(o0+row)*DIM_ + c0 + q);
      Wt[row][q+0] = wv.x; Wt[row][q+1] = wv.y; Wt[row][q+2] = wv.z; Wt[row][q+3] = wv.w;
    }
    {
      const int row = t >> 4, col = (t & 15) << 2;
      *reinterpret_cast<float4*>(&Xt[row][col]) =
        *reinterpret_cast<const float4*>(xb + (size_t)(c0+row)*HW_ + n0 + col);
    }
    __syncthreads();
#pragma unroll
    for (int kk = 0; kk < 16; ++kk){
      const float a0 = Wt[ty*4+0][kk];
      const float a1 = Wt[ty*4+1][kk];
      const float a2 = Wt[ty*4+2][kk];
      const float a3 = Wt[ty*4+3][kk];
      const float4 bv = *reinterpret_cast<const float4*>(&Xt[kk][tx<<2]);
      acc[0][0] = fmaf(a0,bv.x,acc[0][0]); acc[0][1] = fmaf(a0,bv.y,acc[0][1]);
      acc[0][2] = fmaf(a0,bv.z,acc[0][2]); acc[0][3] = fmaf(a0,bv.w,acc[0][3]);
      acc[1][0] = fmaf(a1,bv.x,acc[1][0]); acc[1][1] = fmaf(a1,bv.y,acc[1][1]);
      acc[1][2] = fmaf(a1,bv.z,acc[1][2]); acc[1][3] = fmaf(a1,bv.w,acc[1][3]);
      acc[2][0] = fmaf(a2,bv.x,acc[2][0]); acc[2][1] = fmaf(a2,bv.y,acc[2][1]);
      acc[2][2] = fmaf(a2,bv.z,acc[2][2]); acc[2][3] = fmaf(a2,bv.w,acc[2][3]);
      acc[3][0] = fmaf(a3,bv.x,acc[3][0]); acc[3][1] = fmaf(a3,bv.y,acc[3][1]);
      acc[3][2] = fmaf(a3,bv.z,acc[3][2]); acc[3][3] = fmaf(a3,bv.w,acc[3][3]);
    }
    __syncthreads();
  }
  float* yb = y + (size_t)b * (3*DIM_) * HW_;
#pragma unroll
  for (int i = 0; i < 4; ++i){
    float4 r; r.x = acc[i][0]; r.y = acc[i][1]; r.z = acc[i][2]; r.w = acc[i][3];
    *reinterpret_cast<float4*>(yb + (size_t)(o0+ty*4+i)*HW_ + n0 + (tx<<2)) = r;
  }
}

// ---------------- K1: per (b,head,d) row softmax params ----------------
// prm[bid*3] = {c, m, w_ar[d]/sumexp}; s[d,n] = c * (dwq*dwk), attn = exp(s-m)/sumexp
__global__ __launch_bounds__(256)
void k_rowstats(const float* __restrict__ qkv, const float* __restrict__ w_dw,
                const float* __restrict__ temperature, const float* __restrict__ w_ar,
                float* __restrict__ prm){
  const int bid  = blockIdx.x;                 // b*384 + head*48 + d
  const int d    = bid % D_;
  const int head = (bid / D_) % HEADS_;
  const int b    = bid / (D_*HEADS_);
  const int cq   = head*D_ + d;
  const int ck   = DIM_ + cq;
  const float* qp = qkv + ((size_t)b*(3*DIM_) + cq) * HW_;
  const float* kp = qkv + ((size_t)b*(3*DIM_) + ck) * HW_;
  float wq[9], wk[9];
#pragma unroll
  for (int i = 0; i < 9; ++i){ wq[i] = w_dw[cq*9+i]; wk[i] = w_dw[ck*9+i]; }
  __shared__ float lds[8];
  const int t = threadIdx.x;
  float sq = 0.f, sk = 0.f, pmx = -3.0e38f, pmn = 3.0e38f;
  for (int n = t; n < HW_; n += 256){
    const int y = n >> 6, x = n & 63;
    const float dq = dw3x3(qp, wq, y, x);
    const float dk = dw3x3(kp, wk, y, x);
    sq = fmaf(dq, dq, sq); sk = fmaf(dk, dk, sk);
    const float p = dq*dk;
    pmx = fmaxf(pmx, p); pmn = fminf(pmn, p);
  }
  sq  = block_red<0>(sq, lds);
  sk  = block_red<0>(sk, lds);
  pmx = block_red<1>(pmx, lds);
  pmn = block_red<2>(pmn, lds);
  const float nq = fmaxf(sqrtf(sq), 1e-12f);
  const float nk = fmaxf(sqrtf(sk), 1e-12f);
  const float c  = temperature[head] / (nq*nk);
  const float m  = (c >= 0.f) ? c*pmx : c*pmn;
  float se = 0.f;
  for (int n = t; n < HW_; n += 256){
    const int y = n >> 6, x = n & 63;
    const float dq = dw3x3(qp, wq, y, x);
    const float dk = dw3x3(kp, wk, y, x);
    se += expf(fmaf(c, dq*dk, -m));
  }
  se = block_red<0>(se, lds);
  if (t == 0){
    prm[bid*3+0] = c;
    prm[bid*3+1] = m;
    prm[bid*3+2] = w_ar[d] / se;
  }
}

// ---------------- K2: a[n] = sum_d w_ar[d]*attn[d,n] ----------------
__global__ __launch_bounds__(256)
void k_attn_a(const float* __restrict__ qkv, const float* __restrict__ w_dw,
              const float* __restrict__ prm, float* __restrict__ abuf){
  const int bh   = blockIdx.y;                 // b*8+head
  const int head = bh & 7, b = bh >> 3;
  const int n = blockIdx.x * 256 + threadIdx.x;
  const int y = n >> 6, x = n & 63;
  __shared__ float pc[D_*3];
  __shared__ float wdq[D_*9];
  __shared__ float wdk[D_*9];
  const int t = threadIdx.x;
  for (int i = t; i < D_*3; i += 256) pc[i] = prm[bh*(D_*3) + i];
  for (int i = t; i < D_*9; i += 256){
    wdq[i] = w_dw[(head*D_)*9 + i];
    wdk[i] = w_dw[(DIM_ + head*D_)*9 + i];
  }
  __syncthreads();
  const float* qb = qkv + ((size_t)b*(3*DIM_) + head*D_) * HW_;
  const float* kb = qb + (size_t)DIM_*HW_;
  float a = 0.f;
  for (int d = 0; d < D_; ++d){
    const float dq = dw3x3(qb + (size_t)d*HW_, &wdq[d*9], y, x);
    const float dk = dw3x3(kb + (size_t)d*HW_, &wdk[d*9], y, x);
    a = fmaf(pc[d*3+2], expf(fmaf(pc[d*3+0], dq*dk, -pc[d*3+1])), a);
  }
  abuf[(size_t)bh*HW_ + n] = a;
}

// ---------------- K3: cmask = softmax_n(a) in place ----------------
__global__ __launch_bounds__(256)
void k_cmask(float* __restrict__ abuf){
  const int bh = blockIdx.x;
  float* a = abuf + (size_t)bh*HW_;
  __shared__ float lds[8];
  const int t = threadIdx.x;
  float va[16];
  float mx = -3.0e38f;
#pragma unroll
  for (int i = 0; i < 16; ++i){ va[i] = a[t + i*256]; mx = fmaxf(mx, va[i]); }
  mx = block_red<1>(mx, lds);
  float s = 0.f;
#pragma unroll
  for (int i = 0; i < 16; ++i){ va[i] = expf(va[i]-mx); s += va[i]; }
  s = block_red<0>(s, lds);
  const float inv = 1.f / s;
#pragma unroll
  for (int i = 0; i < 16; ++i) a[t + i*256] = va[i]*inv;
}

// ---------------- K4: vctx[b,head,d] = sum_n cmask[n]*v[d,n] ----------------
__global__ __launch_bounds__(256)
void k_vctx(const float* __restrict__ qkv, const float* __restrict__ w_dw,
            const float* __restrict__ abuf, float* __restrict__ vctx){
  const int bid  = blockIdx.x;                 // b*384 + head*48 + d
  const int d    = bid % D_;
  const int head = (bid / D_) % HEADS_;
  const int b    = bid / (D_*HEADS_);
  const int cv   = 2*DIM_ + head*D_ + d;
  const float* vp = qkv + ((size_t)b*(3*DIM_) + cv)*HW_;
  const float* cm = abuf + ((size_t)(b*HEADS_+head))*HW_;
  float wv[9];
#pragma unroll
  for (int i = 0; i < 9; ++i) wv[i] = w_dw[cv*9+i];
  __shared__ float lds[8];
  const int t = threadIdx.x;
  float s = 0.f;
  for (int n = t; n < HW_; n += 256){
    const int y = n >> 6, x = n & 63;
    s = fmaf(cm[n], dw3x3(vp, wv, y, x), s);
  }
  s = block_red<0>(s, lds);
  if (t == 0) vctx[bid] = s;
}

// ---------------- K5: sp[b,h,n] = sigmoid(sum_d u[d]*v[d,n]) ----------------
// u[d] = sum_o softmax_o(w_al.sum(1)/4096)[o] * w_vl[o,d]   (input-independent)
__global__ __launch_bounds__(256)
void k_spmask(const float* __restrict__ qkv, const float* __restrict__ w_dw,
              const float* __restrict__ w_al, const float* __restrict__ w_vl,
              float* __restrict__ spb){
  const int bh   = blockIdx.y;
  const int head = bh & 7, b = bh >> 3;
  const int n = blockIdx.x*256 + threadIdx.x;
  const int y = n >> 6, x = n & 63;
  const int t = threadIdx.x;
  __shared__ float u[D_];
  __shared__ float avg[DH_];
  __shared__ float wdv[D_*9];
  if (t < DH_){
    float s = 0.f;
    for (int d = 0; d < D_; ++d) s += w_al[t*D_ + d];
    avg[t] = s * (1.f/(float)HW_);
  }
  for (int i = t; i < D_*9; i += 256) wdv[i] = w_dw[(2*DIM_ + head*D_)*9 + i];
  __syncthreads();
  if (t == 0){
    float mx = avg[0];
    for (int o = 1; o < DH_; ++o) mx = fmaxf(mx, avg[o]);
    float s = 0.f;
    for (int o = 0; o < DH_; ++o){ avg[o] = expf(avg[o]-mx); s += avg[o]; }
    const float inv = 1.f/s;
    for (int o = 0; o < DH_; ++o) avg[o] *= inv;
  }
  __syncthreads();
  if (t < D_){
    float s = 0.f;
    for (int o = 0; o < DH_; ++o) s = fmaf(avg[o], w_vl[o*D_ + t], s);
    u[t] = s;
  }
  __syncthreads();
  const float* vb = qkv + ((size_t)b*(3*DIM_) + 2*DIM_ + head*D_)*HW_;
  float acc = 0.f;
  for (int d = 0; d < D_; ++d)
    acc = fmaf(u[d], dw3x3(vb + (size_t)d*HW_, &wdv[d*9], y, x), acc);
  spb[(size_t)bh*HW_ + n] = 1.f/(1.f + expf(-acc));
}

// ---------------- K6: per-b MLP + LayerNorm -> mask_ch[b, c=d*8+head] ----------------
__global__ __launch_bounds__(256)
void k_maskch(const float* __restrict__ vctx, const float* __restrict__ w_vr,
              const float* __restrict__ w_up1, const float* __restrict__ b_up1,
              const float* __restrict__ ln_g, const float* __restrict__ ln_b,
              const float* __restrict__ w_up2, const float* __restrict__ b_up2,
              float* __restrict__ mch){
  const int b = blockIdx.x;
  const int t = threadIdx.x;
  __shared__ float vc[HEADS_*D_];   // [head][d]
  __shared__ float cx[HEADS_*DH_];  // [head][o]
  __shared__ float t1[D2_*HEADS_];  // [o2][head] == flat [D2,8,1]
  __shared__ float lds[8];
  for (int i = t; i < HEADS_*D_; i += 256) vc[i] = vctx[b*HEADS_*D_ + i];
  __syncthreads();
  if (t < HEADS_*DH_){
    const int head = t / DH_, o = t % DH_;
    float s = 0.f;
    for (int d = 0; d < D_; ++d) s = fmaf(w_vr[o*D_+d], vc[head*D_+d], s);
    cx[head*DH_+o] = s;
  }
  __syncthreads();
  const int o2 = t >> 3, hh = t & 7;   // t = o2*8 + head, exactly 256 = 32*8
  float val = b_up1[o2];
  for (int o = 0; o < DH_; ++o) val = fmaf(w_up1[o2*DH_+o], cx[hh*DH_+o], val);
  const float mu  = block_red<0>(val, lds) * (1.f/256.f);
  const float dv  = val - mu;
  const float var = block_red<0>(dv*dv, lds) * (1.f/256.f);
  float yv = dv / sqrtf(var + 1e-5f);
  yv = fmaf(yv, ln_g[t], ln_b[t]);
  yv = fmaxf(yv, 0.f);
  t1[t] = yv;
  __syncthreads();
  for (int idx = t; idx < D_*HEADS_; idx += 256){
    const int d = idx >> 3, head2 = idx & 7;
    float s = b_up2[d];
    for (int o = 0; o < D2_; ++o) s = fmaf(w_up2[d*D2_+o], t1[o*HEADS_+head2], s);
    mch[b*DIM_ + idx] = 1.f/(1.f + expf(-s));   // c = d*8+head (reference reshape)
  }
}

// ---------------- K7: out = x * (mask_ch[b,c] + sum_h w_proj[c,h]*sp[b,h,n]) ----------------
__global__ __launch_bounds__(256)
void k_out(const float* __restrict__ x, const float* __restrict__ spb,
           const float* __restrict__ mch, const float* __restrict__ w_proj,
           float* __restrict__ out){
  const int b  = blockIdx.z;
  const int c0 = blockIdx.y * 16;
  const int n  = blockIdx.x * 256 + threadIdx.x;
  float sv[8];
#pragma unroll
  for (int h = 0; h < 8; ++h) sv[h] = spb[((size_t)(b*8+h))*HW_ + n];
  for (int ci = 0; ci < 16; ++ci){
    const int c = c0 + ci;
    float g = mch[b*DIM_ + c];
#pragma unroll
    for (int h = 0; h < 8; ++h) g = fmaf(w_proj[c*8+h], sv[h], g);
    const size_t off = ((size_t)b*DIM_ + c)*HW_ + n;
    out[off] = x[off] * g;
  }
}

extern "C" void kernel_launch(void* const* d_in, const int* in_sizes, int n_in,
                              void* d_out, int out_size, void* d_ws, size_t ws_size,
                              hipStream_t stream) {
  const float* x      = (const float*)d_in[0];
  const float* w_qkv  = (const float*)d_in[1];
  const float* w_dw   = (const float*)d_in[2];
  const float* temp   = (const float*)d_in[3];
  const float* w_ar   = (const float*)d_in[4];
  const float* w_vr   = (const float*)d_in[5];
  const float* w_up1  = (const float*)d_in[6];
  const float* b_up1  = (const float*)d_in[7];
  const float* ln_g   = (const float*)d_in[8];
  const float* ln_b   = (const float*)d_in[9];
  const float* w_up2  = (const float*)d_in[10];
  const float* b_up2  = (const float*)d_in[11];
  const float* w_al   = (const float*)d_in[12];
  const float* w_vl   = (const float*)d_in[13];
  const float* w_proj = (const float*)d_in[14];
  float* out = (float*)d_out;

  // workspace layout (floats)
  float* ws   = (float*)d_ws;
  float* qkv  = ws;                                   // 8*1152*4096
  float* prm  = qkv  + (size_t)B_*3*DIM_*HW_;         // 3072*3
  float* abuf = prm  + (size_t)B_*HEADS_*D_*3;        // 64*4096
  float* vctx = abuf + (size_t)B_*HEADS_*HW_;         // 3072
  float* spb  = vctx + (size_t)B_*HEADS_*D_;          // 64*4096
  float* mch  = spb  + (size_t)B_*HEADS_*HW_;         // 8*384

  k_conv1x1<<<dim3(HW_/64, (3*DIM_)/64, B_), 256, 0, stream>>>(x, w_qkv, qkv);
  k_rowstats<<<dim3(B_*HEADS_*D_), 256, 0, stream>>>(qkv, w_dw, temp, w_ar, prm);
  k_attn_a<<<dim3(HW_/256, B_*HEADS_), 256, 0, stream>>>(qkv, w_dw, prm, abuf);
  k_cmask<<<dim3(B_*HEADS_), 256, 0, stream>>>(abuf);
  k_vctx<<<dim3(B_*HEADS_*D_), 256, 0, stream>>>(qkv, w_dw, abuf, vctx);
  k_spmask<<<dim3(HW_/256, B_*HEADS_), 256, 0, stream>>>(qkv, w_dw, w_al, w_vl, spb);
  k_maskch<<<dim3(B_), 256, 0, stream>>>(vctx, w_vr, w_up1, b_up1, ln_g, ln_b,
                                         w_up2, b_up2, mch);
  k_out<<<dim3(HW_/256, DIM_/16, B_), 256, 0, stream>>>(x, spb, mch, w_proj, out);
}

// Round 2
// 354.931 us; speedup vs baseline: 3.1448x; 3.1448x over previous
//
#include <hip/hip_runtime.h>
#include <math.h>
#include <stdint.h>

#define B_     8
#define DIM_   384
#define HEADS_ 8
#define D_     48
#define DH_    24
#define D2_    32
#define HW_    4096
#define IMG    64
#define CH3    1152   // 3*DIM

typedef __attribute__((ext_vector_type(8))) __bf16   bf16x8;
typedef __attribute__((ext_vector_type(4))) float    f32x4;
typedef __attribute__((ext_vector_type(8))) unsigned short u16x8;

__device__ __forceinline__ float b2f(unsigned short h){
  union { uint32_t u; float f; } v; v.u = ((uint32_t)h) << 16; return v.f;
}
__device__ __forceinline__ unsigned short f2b(float f){
  union { float f; uint32_t u; } v; v.f = f;
  uint32_t r = v.u + 0x7fffu + ((v.u >> 16) & 1u);   // RNE
  return (unsigned short)(r >> 16);
}

// ---------------- reduction helpers ----------------
__device__ __forceinline__ float wred_sum(float v){
#pragma unroll
  for (int m = 32; m; m >>= 1) v += __shfl_xor(v, m);
  return v;
}
__device__ __forceinline__ float wred_max(float v){
#pragma unroll
  for (int m = 32; m; m >>= 1) v = fmaxf(v, __shfl_xor(v, m));
  return v;
}
__device__ __forceinline__ float wred_min(float v){
#pragma unroll
  for (int m = 32; m; m >>= 1) v = fminf(v, __shfl_xor(v, m));
  return v;
}
template<int OP>  // 0=sum 1=max 2=min
__device__ __forceinline__ float block_red(float v, float* lds){
  if (OP == 0) v = wred_sum(v);
  else if (OP == 1) v = wred_max(v);
  else v = wred_min(v);
  const int lane = threadIdx.x & 63;
  const int wid  = threadIdx.x >> 6;
  __syncthreads();
  if (lane == 0) lds[wid] = v;
  __syncthreads();
  const int nw = blockDim.x >> 6;
  float r = lds[0];
  for (int i = 1; i < nw; ++i){
    float o = lds[i];
    if (OP == 0) r += o; else if (OP == 1) r = fmaxf(r, o); else r = fminf(r, o);
  }
  return r;
}

// ---------------- P0a: w_qkv -> bf16 ----------------
__global__ __launch_bounds__(256)
void k_cvtw(const float* __restrict__ w, unsigned short* __restrict__ wb){
  const int i = (blockIdx.x * 256 + threadIdx.x) * 4;   // 1152*384 = 442368 = 432*256*4
  float4 v = *reinterpret_cast<const float4*>(w + i);
  wb[i+0] = f2b(v.x); wb[i+1] = f2b(v.y); wb[i+2] = f2b(v.z); wb[i+3] = f2b(v.w);
}

// ---------------- P0b: x [b,384,4096] f32 -> xT [b,4096,384] bf16 ----------------
__global__ __launch_bounds__(256)
void k_prep(const float* __restrict__ x, unsigned short* __restrict__ xT){
  __shared__ unsigned short Ts[64][66];
  const int t = threadIdx.x;
  const float* xb = x + ((size_t)blockIdx.z * DIM_ + blockIdx.y * 64) * HW_ + blockIdx.x * 64;
#pragma unroll
  for (int rr = 0; rr < 4; ++rr){
    const int r = (t >> 4) + rr * 16;
    const int c = (t & 15) * 4;
    float4 v = *reinterpret_cast<const float4*>(xb + (size_t)r * HW_ + c);
    Ts[r][c+0] = f2b(v.x); Ts[r][c+1] = f2b(v.y); Ts[r][c+2] = f2b(v.z); Ts[r][c+3] = f2b(v.w);
  }
  __syncthreads();
  const int rn = t >> 2, kc = (t & 3) * 16;
  unsigned short* yb = xT + ((size_t)blockIdx.z * HW_ + blockIdx.x * 64 + rn) * DIM_
                          + blockIdx.y * 64 + kc;
  u16x8 o0, o1;
#pragma unroll
  for (int j = 0; j < 8; ++j){ o0[j] = Ts[kc + j][rn]; o1[j] = Ts[kc + 8 + j][rn]; }
  *reinterpret_cast<u16x8*>(yb)     = o0;
  *reinterpret_cast<u16x8*>(yb + 8) = o1;
}

// ---------------- K0: qkv[b,m,n] = sum_k wb[m,k]*xT[b,n,k]  (bf16 MFMA) ----------------
// 128x128 tile, BK=64, 4 waves each 64x64 (4x4 frags of 16x16x32)
__global__ __launch_bounds__(256, 2)
void k_gemm(const unsigned short* __restrict__ wb, const unsigned short* __restrict__ xT,
            unsigned short* __restrict__ qkv){
  const int b  = blockIdx.z;
  const int m0 = blockIdx.y * 128;
  const int n0 = blockIdx.x * 128;
  __shared__ unsigned short As[128 * 64];
  __shared__ unsigned short Bs[128 * 64];
  const int t = threadIdx.x;
  const int lane = t & 63;
  const int w = t >> 6, wr = w >> 1, wc = w & 1;
  f32x4 acc[4][4];
#pragma unroll
  for (int i = 0; i < 4; ++i)
#pragma unroll
    for (int j = 0; j < 4; ++j) acc[i][j] = (f32x4){0.f,0.f,0.f,0.f};

  const unsigned short* Ag = wb + (size_t)m0 * DIM_;
  const unsigned short* Bg = xT + ((size_t)b * HW_ + n0) * DIM_;

  for (int k0 = 0; k0 < DIM_; k0 += 64){
#pragma unroll
    for (int i = 0; i < 4; ++i){
      const int q = i * 256 + t;          // 16B chunk id, 1024 chunks = 16KB tile
      const int qb = q & ~63;             // wave-uniform base chunk
      const int r = q >> 3, c = q & 7;    // row (128B = 8 chunks), chunk-in-row
      __builtin_amdgcn_global_load_lds(
        (const __attribute__((address_space(1))) void*)(Ag + (size_t)r * DIM_ + k0 + c * 8),
        (__attribute__((address_space(3))) void*)(As + qb * 8), 16, 0, 0);
    }
#pragma unroll
    for (int i = 0; i < 4; ++i){
      const int q = i * 256 + t;
      const int qb = q & ~63;
      const int r = q >> 3, c = q & 7;
      __builtin_amdgcn_global_load_lds(
        (const __attribute__((address_space(1))) void*)(Bg + (size_t)r * DIM_ + k0 + c * 8),
        (__attribute__((address_space(3))) void*)(Bs + qb * 8), 16, 0, 0);
    }
    __syncthreads();
#pragma unroll
    for (int ks = 0; ks < 2; ++ks){
      const int kb = ks * 32 + (lane >> 4) * 8;
      bf16x8 af[4], bfr[4];
#pragma unroll
      for (int mi = 0; mi < 4; ++mi){
        const int row = wr * 64 + mi * 16 + (lane & 15);
        af[mi] = *reinterpret_cast<const bf16x8*>(As + row * 64 + kb);
      }
#pragma unroll
      for (int ni = 0; ni < 4; ++ni){
        const int row = wc * 64 + ni * 16 + (lane & 15);
        bfr[ni] = *reinterpret_cast<const bf16x8*>(Bs + row * 64 + kb);
      }
#pragma unroll
      for (int mi = 0; mi < 4; ++mi)
#pragma unroll
        for (int ni = 0; ni < 4; ++ni)
          acc[mi][ni] = __builtin_amdgcn_mfma_f32_16x16x32_bf16(af[mi], bfr[ni], acc[mi][ni], 0, 0, 0);
    }
    __syncthreads();
  }
  // epilogue: C/D layout col=lane&15, row=(lane>>4)*4+reg  [m89-verified]
  unsigned short* yb = qkv + ((size_t)b * CH3 + m0) * HW_ + n0;
#pragma unroll
  for (int mi = 0; mi < 4; ++mi){
    const int rbase = wr * 64 + mi * 16 + (lane >> 4) * 4;
#pragma unroll
    for (int ni = 0; ni < 4; ++ni){
      const int col = wc * 64 + ni * 16 + (lane & 15);
#pragma unroll
      for (int r = 0; r < 4; ++r)
        yb[(size_t)(rbase + r) * HW_ + col] = f2b(acc[mi][ni][r]);
    }
  }
}

// ---------------- K1: depthwise 3x3 in-place on each bf16 plane ----------------
__global__ __launch_bounds__(256)
void k_dwconv(unsigned short* __restrict__ qkv, const float* __restrict__ w_dw){
  const int pc = blockIdx.x;               // b*1152 + ch
  const int ch = pc % CH3;
  unsigned short* plane = qkv + (size_t)pc * HW_;
  __shared__ float P[HW_];
  const int t = threadIdx.x;
  {
    u16x8 v0 = *reinterpret_cast<const u16x8*>(plane + t * 16);
    u16x8 v1 = *reinterpret_cast<const u16x8*>(plane + t * 16 + 8);
    float4 f;
#pragma unroll
    for (int j = 0; j < 8; j += 4){
      f.x = b2f(v0[j]); f.y = b2f(v0[j+1]); f.z = b2f(v0[j+2]); f.w = b2f(v0[j+3]);
      *reinterpret_cast<float4*>(&P[t*16 + j]) = f;
    }
#pragma unroll
    for (int j = 0; j < 8; j += 4){
      f.x = b2f(v1[j]); f.y = b2f(v1[j+1]); f.z = b2f(v1[j+2]); f.w = b2f(v1[j+3]);
      *reinterpret_cast<float4*>(&P[t*16 + 8 + j]) = f;
    }
  }
  float w9[9];
#pragma unroll
  for (int i = 0; i < 9; ++i) w9[i] = w_dw[ch * 9 + i];
  __syncthreads();
  const int y  = t >> 2;
  const int x0 = (t & 3) * 16;
  float acc16[16];
#pragma unroll
  for (int j = 0; j < 16; ++j) acc16[j] = 0.f;
#pragma unroll
  for (int dy = -1; dy <= 1; ++dy){
    const int yy = y + dy;
    if ((unsigned)yy >= (unsigned)IMG) continue;
    float rw[18];
#pragma unroll
    for (int j = 0; j < 18; ++j){
      const int xx = x0 - 1 + j;
      rw[j] = ((unsigned)xx < (unsigned)IMG) ? P[yy * IMG + xx] : 0.f;
    }
    const float w0 = w9[(dy+1)*3], w1 = w9[(dy+1)*3+1], w2 = w9[(dy+1)*3+2];
#pragma unroll
    for (int j = 0; j < 16; ++j)
      acc16[j] = fmaf(rw[j], w0, fmaf(rw[j+1], w1, fmaf(rw[j+2], w2, acc16[j])));
  }
  u16x8 o0, o1;
#pragma unroll
  for (int j = 0; j < 8; ++j){ o0[j] = f2b(acc16[j]); o1[j] = f2b(acc16[8+j]); }
  *reinterpret_cast<u16x8*>(plane + t * 16)     = o0;
  *reinterpret_cast<u16x8*>(plane + t * 16 + 8) = o1;
}

// ---------------- K2: per (b,head,d) softmax params ----------------
__global__ __launch_bounds__(256)
void k_rowstats(const unsigned short* __restrict__ dqkv, const float* __restrict__ temperature,
                const float* __restrict__ w_ar, float* __restrict__ prm){
  const int bid  = blockIdx.x;             // b*384 + head*48 + d
  const int d    = bid % D_;
  const int head = (bid / D_) % HEADS_;
  const int b    = bid / (D_ * HEADS_);
  const int cq   = head * D_ + d;
  const unsigned short* qp = dqkv + ((size_t)b * CH3 + cq) * HW_;
  const unsigned short* kp = qp + (size_t)DIM_ * HW_;
  __shared__ float lds[8];
  const int t = threadIdx.x;
  float p[16];
  float sq = 0.f, sk = 0.f, pmx = -3.0e38f, pmn = 3.0e38f;
  {
    u16x8 q0 = *reinterpret_cast<const u16x8*>(qp + t * 16);
    u16x8 q1 = *reinterpret_cast<const u16x8*>(qp + t * 16 + 8);
    u16x8 k0 = *reinterpret_cast<const u16x8*>(kp + t * 16);
    u16x8 k1 = *reinterpret_cast<const u16x8*>(kp + t * 16 + 8);
#pragma unroll
    for (int j = 0; j < 8; ++j){
      float fq = b2f(q0[j]), fk = b2f(k0[j]);
      sq = fmaf(fq, fq, sq); sk = fmaf(fk, fk, sk);
      p[j] = fq * fk; pmx = fmaxf(pmx, p[j]); pmn = fminf(pmn, p[j]);
    }
#pragma unroll
    for (int j = 0; j < 8; ++j){
      float fq = b2f(q1[j]), fk = b2f(k1[j]);
      sq = fmaf(fq, fq, sq); sk = fmaf(fk, fk, sk);
      p[8+j] = fq * fk; pmx = fmaxf(pmx, p[8+j]); pmn = fminf(pmn, p[8+j]);
    }
  }
  sq  = block_red<0>(sq, lds);
  sk  = block_red<0>(sk, lds);
  pmx = block_red<1>(pmx, lds);
  pmn = block_red<2>(pmn, lds);
  const float nq = fmaxf(sqrtf(sq), 1e-12f);
  const float nk = fmaxf(sqrtf(sk), 1e-12f);
  const float c  = temperature[head] / (nq * nk);
  const float m  = (c >= 0.f) ? c * pmx : c * pmn;
  float se = 0.f;
#pragma unroll
  for (int j = 0; j < 16; ++j) se += expf(fmaf(c, p[j], -m));
  se = block_red<0>(se, lds);
  if (t == 0){
    prm[bid*3+0] = c;
    prm[bid*3+1] = m;
    prm[bid*3+2] = w_ar[d] / se;
  }
}

// ---------------- K3: a[n] = sum_d (w_ar[d]/se_d) * exp(c_d*p - m_d) ----------------
__global__ __launch_bounds__(256)
void k_attn_a(const unsigned short* __restrict__ dqkv, const float* __restrict__ prm,
              float* __restrict__ abuf){
  const int bh   = blockIdx.y;
  const int head = bh & 7, b = bh >> 3;
  const int t = threadIdx.x;
  const int px0 = blockIdx.x * 2048 + t * 8;
  __shared__ float pc[D_ * 3];
  for (int i = t; i < D_ * 3; i += 256) pc[i] = prm[bh * (D_ * 3) + i];
  __syncthreads();
  const unsigned short* qb = dqkv + ((size_t)b * CH3 + head * D_) * HW_ + px0;
  const unsigned short* kb = qb + (size_t)DIM_ * HW_;
  float a[8];
#pragma unroll
  for (int j = 0; j < 8; ++j) a[j] = 0.f;
  for (int d = 0; d < D_; ++d){
    u16x8 vq = *reinterpret_cast<const u16x8*>(qb + (size_t)d * HW_);
    u16x8 vk = *reinterpret_cast<const u16x8*>(kb + (size_t)d * HW_);
    const float cc = pc[d*3], mm = pc[d*3+1], ww = pc[d*3+2];
#pragma unroll
    for (int j = 0; j < 8; ++j)
      a[j] = fmaf(ww, expf(fmaf(cc, b2f(vq[j]) * b2f(vk[j]), -mm)), a[j]);
  }
  float* ob = abuf + (size_t)bh * HW_ + px0;
  float4 o;
  o.x = a[0]; o.y = a[1]; o.z = a[2]; o.w = a[3];
  *reinterpret_cast<float4*>(ob) = o;
  o.x = a[4]; o.y = a[5]; o.z = a[6]; o.w = a[7];
  *reinterpret_cast<float4*>(ob + 4) = o;
}

// ---------------- K4: cmask = softmax_n(a) in place ----------------
__global__ __launch_bounds__(256)
void k_cmask(float* __restrict__ abuf){
  const int bh = blockIdx.x;
  float* a = abuf + (size_t)bh * HW_;
  __shared__ float lds[8];
  const int t = threadIdx.x;
  float va[16];
  float mx = -3.0e38f;
#pragma unroll
  for (int i = 0; i < 16; ++i){ va[i] = a[t + i*256]; mx = fmaxf(mx, va[i]); }
  mx = block_red<1>(mx, lds);
  float s = 0.f;
#pragma unroll
  for (int i = 0; i < 16; ++i){ va[i] = expf(va[i]-mx); s += va[i]; }
  s = block_red<0>(s, lds);
  const float inv = 1.f / s;
#pragma unroll
  for (int i = 0; i < 16; ++i) a[t + i*256] = va[i]*inv;
}

// ---------------- K5: vctx[b,head,d] = sum_n cmask[n]*dv[d,n] ----------------
__global__ __launch_bounds__(256)
void k_vctx(const unsigned short* __restrict__ dqkv, const float* __restrict__ abuf,
            float* __restrict__ vctx){
  const int bid  = blockIdx.x;
  const int d    = bid % D_;
  const int head = (bid / D_) % HEADS_;
  const int b    = bid / (D_ * HEADS_);
  const unsigned short* vp = dqkv + ((size_t)b * CH3 + 2*DIM_ + head*D_ + d) * HW_;
  const float* cm = abuf + ((size_t)(b * HEADS_ + head)) * HW_;
  __shared__ float lds[8];
  const int t = threadIdx.x;
  float s = 0.f;
  u16x8 v0 = *reinterpret_cast<const u16x8*>(vp + t * 16);
  u16x8 v1 = *reinterpret_cast<const u16x8*>(vp + t * 16 + 8);
#pragma unroll
  for (int j = 0; j < 8; ++j) s = fmaf(cm[t*16 + j],     b2f(v0[j]), s);
#pragma unroll
  for (int j = 0; j < 8; ++j) s = fmaf(cm[t*16 + 8 + j], b2f(v1[j]), s);
  s = block_red<0>(s, lds);
  if (t == 0) vctx[bid] = s;
}

// ---------------- K6: sp[b,h,n] = sigmoid(sum_d u[d]*dv[d,n]) ----------------
__global__ __launch_bounds__(256)
void k_spmask(const unsigned short* __restrict__ dqkv, const float* __restrict__ w_al,
              const float* __restrict__ w_vl, float* __restrict__ spb){
  const int bh   = blockIdx.y;
  const int head = bh & 7, b = bh >> 3;
  const int t = threadIdx.x;
  const int px0 = blockIdx.x * 2048 + t * 8;
  __shared__ float u[D_];
  __shared__ float avg[DH_];
  if (t < DH_){
    float s = 0.f;
    for (int d = 0; d < D_; ++d) s += w_al[t*D_ + d];
    avg[t] = s * (1.f/(float)HW_);
  }
  __syncthreads();
  if (t == 0){
    float mx = avg[0];
    for (int o = 1; o < DH_; ++o) mx = fmaxf(mx, avg[o]);
    float s = 0.f;
    for (int o = 0; o < DH_; ++o){ avg[o] = expf(avg[o]-mx); s += avg[o]; }
    const float inv = 1.f/s;
    for (int o = 0; o < DH_; ++o) avg[o] *= inv;
  }
  __syncthreads();
  if (t < D_){
    float s = 0.f;
    for (int o = 0; o < DH_; ++o) s = fmaf(avg[o], w_vl[o*D_ + t], s);
    u[t] = s;
  }
  __syncthreads();
  const unsigned short* vb = dqkv + ((size_t)b * CH3 + 2*DIM_ + head*D_) * HW_ + px0;
  float acc[8];
#pragma unroll
  for (int j = 0; j < 8; ++j) acc[j] = 0.f;
  for (int d = 0; d < D_; ++d){
    u16x8 vv = *reinterpret_cast<const u16x8*>(vb + (size_t)d * HW_);
    const float ud = u[d];
#pragma unroll
    for (int j = 0; j < 8; ++j) acc[j] = fmaf(ud, b2f(vv[j]), acc[j]);
  }
  float* ob = spb + (size_t)bh * HW_ + px0;
  float4 o;
  o.x = 1.f/(1.f+expf(-acc[0])); o.y = 1.f/(1.f+expf(-acc[1]));
  o.z = 1.f/(1.f+expf(-acc[2])); o.w = 1.f/(1.f+expf(-acc[3]));
  *reinterpret_cast<float4*>(ob) = o;
  o.x = 1.f/(1.f+expf(-acc[4])); o.y = 1.f/(1.f+expf(-acc[5]));
  o.z = 1.f/(1.f+expf(-acc[6])); o.w = 1.f/(1.f+expf(-acc[7]));
  *reinterpret_cast<float4*>(ob + 4) = o;
}

// ---------------- K7: per-b MLP + LayerNorm -> mask_ch[b, c=d*8+head] ----------------
__global__ __launch_bounds__(256)
void k_maskch(const float* __restrict__ vctx, const float* __restrict__ w_vr,
              const float* __restrict__ w_up1, const float* __restrict__ b_up1,
              const float* __restrict__ ln_g, const float* __restrict__ ln_b,
              const float* __restrict__ w_up2, const float* __restrict__ b_up2,
              float* __restrict__ mch){
  const int b = blockIdx.x;
  const int t = threadIdx.x;
  __shared__ float vc[HEADS_*D_];
  __shared__ float cx[HEADS_*DH_];
  __shared__ float t1[D2_*HEADS_];
  __shared__ float lds[8];
  for (int i = t; i < HEADS_*D_; i += 256) vc[i] = vctx[b*HEADS_*D_ + i];
  __syncthreads();
  if (t < HEADS_*DH_){
    const int head = t / DH_, o = t % DH_;
    float s = 0.f;
    for (int d = 0; d < D_; ++d) s = fmaf(w_vr[o*D_+d], vc[head*D_+d], s);
    cx[head*DH_+o] = s;
  }
  __syncthreads();
  const int o2 = t >> 3, hh = t & 7;
  float val = b_up1[o2];
  for (int o = 0; o < DH_; ++o) val = fmaf(w_up1[o2*DH_+o], cx[hh*DH_+o], val);
  const float mu  = block_red<0>(val, lds) * (1.f/256.f);
  const float dv  = val - mu;
  const float var = block_red<0>(dv*dv, lds) * (1.f/256.f);
  float yv = dv / sqrtf(var + 1e-5f);
  yv = fmaf(yv, ln_g[t], ln_b[t]);
  yv = fmaxf(yv, 0.f);
  t1[t] = yv;
  __syncthreads();
  for (int idx = t; idx < D_*HEADS_; idx += 256){
    const int d = idx >> 3, head2 = idx & 7;
    float s = b_up2[d];
    for (int o = 0; o < D2_; ++o) s = fmaf(w_up2[d*D2_+o], t1[o*HEADS_+head2], s);
    mch[b*DIM_ + idx] = 1.f/(1.f + expf(-s));
  }
}

// ---------------- K8: out = x * (mask_ch + sum_h w_proj*sp) ----------------
__global__ __launch_bounds__(256)
void k_out(const float* __restrict__ x, const float* __restrict__ spb,
           const float* __restrict__ mch, const float* __restrict__ w_proj,
           float* __restrict__ out){
  const int b  = blockIdx.z;
  const int c0 = blockIdx.y * 16;
  const int n  = blockIdx.x * 1024 + threadIdx.x * 4;
  float4 sv[8];
#pragma unroll
  for (int h = 0; h < 8; ++h)
    sv[h] = *reinterpret_cast<const float4*>(spb + ((size_t)(b*8+h))*HW_ + n);
  for (int ci = 0; ci < 16; ++ci){
    const int c = c0 + ci;
    const float g = mch[b*DIM_ + c];
    float4 gv; gv.x = g; gv.y = g; gv.z = g; gv.w = g;
#pragma unroll
    for (int h = 0; h < 8; ++h){
      const float wp = w_proj[c*8+h];
      gv.x = fmaf(wp, sv[h].x, gv.x); gv.y = fmaf(wp, sv[h].y, gv.y);
      gv.z = fmaf(wp, sv[h].z, gv.z); gv.w = fmaf(wp, sv[h].w, gv.w);
    }
    const size_t off = ((size_t)b*DIM_ + c)*HW_ + n;
    float4 xv = *reinterpret_cast<const float4*>(x + off);
    xv.x *= gv.x; xv.y *= gv.y; xv.z *= gv.z; xv.w *= gv.w;
    *reinterpret_cast<float4*>(out + off) = xv;
  }
}

extern "C" void kernel_launch(void* const* d_in, const int* in_sizes, int n_in,
                              void* d_out, int out_size, void* d_ws, size_t ws_size,
                              hipStream_t stream) {
  const float* x      = (const float*)d_in[0];
  const float* w_qkv  = (const float*)d_in[1];
  const float* w_dw   = (const float*)d_in[2];
  const float* temp   = (const float*)d_in[3];
  const float* w_ar   = (const float*)d_in[4];
  const float* w_vr   = (const float*)d_in[5];
  const float* w_up1  = (const float*)d_in[6];
  const float* b_up1  = (const float*)d_in[7];
  const float* ln_g   = (const float*)d_in[8];
  const float* ln_b   = (const float*)d_in[9];
  const float* w_up2  = (const float*)d_in[10];
  const float* b_up2  = (const float*)d_in[11];
  const float* w_al   = (const float*)d_in[12];
  const float* w_vl   = (const float*)d_in[13];
  const float* w_proj = (const float*)d_in[14];
  float* out = (float*)d_out;

  // workspace layout (all 16B-aligned)
  unsigned short* qkvb = (unsigned short*)d_ws;              // 8*1152*4096 bf16 (qkv, then dwconv in-place)
  unsigned short* xT   = qkvb + (size_t)B_*CH3*HW_;          // 8*4096*384 bf16
  unsigned short* wb   = xT + (size_t)B_*HW_*DIM_;           // 1152*384 bf16
  float* prm  = (float*)(wb + (size_t)CH3*DIM_);             // 3072*3
  float* abuf = prm + 3*B_*HEADS_*D_;                        // 64*4096
  float* vctx = abuf + (size_t)B_*HEADS_*HW_;                // 3072
  float* spb  = vctx + B_*HEADS_*D_;                         // 64*4096
  float* mch  = spb + (size_t)B_*HEADS_*HW_;                 // 8*384

  k_cvtw<<<dim3((CH3*DIM_)/1024), 256, 0, stream>>>(w_qkv, wb);
  k_prep<<<dim3(HW_/64, DIM_/64, B_), 256, 0, stream>>>(x, xT);
  k_gemm<<<dim3(HW_/128, CH3/128, B_), 256, 0, stream>>>(wb, xT, qkvb);
  k_dwconv<<<dim3(B_*CH3), 256, 0, stream>>>(qkvb, w_dw);
  k_rowstats<<<dim3(B_*HEADS_*D_), 256, 0, stream>>>(qkvb, temp, w_ar, prm);
  k_attn_a<<<dim3(2, B_*HEADS_), 256, 0, stream>>>(qkvb, prm, abuf);
  k_cmask<<<dim3(B_*HEADS_), 256, 0, stream>>>(abuf);
  k_vctx<<<dim3(B_*HEADS_*D_), 256, 0, stream>>>(qkvb, abuf, vctx);
  k_spmask<<<dim3(2, B_*HEADS_), 256, 0, stream>>>(qkvb, w_al, w_vl, spb);
  k_maskch<<<dim3(B_), 256, 0, stream>>>(vctx, w_vr, w_up1, b_up1, ln_g, ln_b,
                                         w_up2, b_up2, mch);
  k_out<<<dim3(HW_/1024, DIM_/16, B_), 256, 0, stream>>>(x, spb, mch, w_proj, out);
}

// Round 3
// 265.384 us; speedup vs baseline: 4.2059x; 1.3374x over previous
//
#include <hip/hip_runtime.h>
#include <math.h>
#include <stdint.h>

#define B_     8
#define DIM_   384
#define HEADS_ 8
#define D_     48
#define DH_    24
#define D2_    32
#define HW_    4096
#define IMG    64
#define CH3    1152   // 3*DIM

typedef __attribute__((ext_vector_type(8))) __bf16   bf16x8;
typedef __attribute__((ext_vector_type(4))) float    f32x4;
typedef __attribute__((ext_vector_type(8))) unsigned short u16x8;

__device__ __forceinline__ float b2f(unsigned short h){
  union { uint32_t u; float f; } v; v.u = ((uint32_t)h) << 16; return v.f;
}
__device__ __forceinline__ unsigned short f2b(float f){
  union { float f; uint32_t u; } v; v.f = f;
  uint32_t r = v.u + 0x7fffu + ((v.u >> 16) & 1u);   // RNE
  return (unsigned short)(r >> 16);
}

// ---------------- reduction helpers ----------------
__device__ __forceinline__ float wred_sum(float v){
#pragma unroll
  for (int m = 32; m; m >>= 1) v += __shfl_xor(v, m);
  return v;
}
__device__ __forceinline__ float wred_max(float v){
#pragma unroll
  for (int m = 32; m; m >>= 1) v = fmaxf(v, __shfl_xor(v, m));
  return v;
}
__device__ __forceinline__ float wred_min(float v){
#pragma unroll
  for (int m = 32; m; m >>= 1) v = fminf(v, __shfl_xor(v, m));
  return v;
}
template<int OP>  // 0=sum 1=max 2=min
__device__ __forceinline__ float block_red(float v, float* lds){
  if (OP == 0) v = wred_sum(v);
  else if (OP == 1) v = wred_max(v);
  else v = wred_min(v);
  const int lane = threadIdx.x & 63;
  const int wid  = threadIdx.x >> 6;
  __syncthreads();
  if (lane == 0) lds[wid] = v;
  __syncthreads();
  const int nw = blockDim.x >> 6;
  float r = lds[0];
  for (int i = 1; i < nw; ++i){
    float o = lds[i];
    if (OP == 0) r += o; else if (OP == 1) r = fmaxf(r, o); else r = fminf(r, o);
  }
  return r;
}

// ---------------- P0a: w_qkv -> bf16 ----------------
__global__ __launch_bounds__(256)
void k_cvtw(const float* __restrict__ w, unsigned short* __restrict__ wb){
  const int i = (blockIdx.x * 256 + threadIdx.x) * 4;
  float4 v = *reinterpret_cast<const float4*>(w + i);
  wb[i+0] = f2b(v.x); wb[i+1] = f2b(v.y); wb[i+2] = f2b(v.z); wb[i+3] = f2b(v.w);
}

// ---------------- P0b: x [b,384,4096] f32 -> xT [b,4096,384] bf16 ----------------
__global__ __launch_bounds__(256)
void k_prep(const float* __restrict__ x, unsigned short* __restrict__ xT){
  __shared__ unsigned short Ts[64][66];
  const int t = threadIdx.x;
  const float* xb = x + ((size_t)blockIdx.z * DIM_ + blockIdx.y * 64) * HW_ + blockIdx.x * 64;
#pragma unroll
  for (int rr = 0; rr < 4; ++rr){
    const int r = (t >> 4) + rr * 16;
    const int c = (t & 15) * 4;
    float4 v = *reinterpret_cast<const float4*>(xb + (size_t)r * HW_ + c);
    Ts[r][c+0] = f2b(v.x); Ts[r][c+1] = f2b(v.y); Ts[r][c+2] = f2b(v.z); Ts[r][c+3] = f2b(v.w);
  }
  __syncthreads();
  const int rn = t >> 2, kc = (t & 3) * 16;
  unsigned short* yb = xT + ((size_t)blockIdx.z * HW_ + blockIdx.x * 64 + rn) * DIM_
                          + blockIdx.y * 64 + kc;
  u16x8 o0, o1;
#pragma unroll
  for (int j = 0; j < 8; ++j){ o0[j] = Ts[kc + j][rn]; o1[j] = Ts[kc + 8 + j][rn]; }
  *reinterpret_cast<u16x8*>(yb)     = o0;
  *reinterpret_cast<u16x8*>(yb + 8) = o1;
}

// ---------------- K0: qkv[b,m,n] = sum_k wb[m,k]*xT[b,n,k]  (bf16 MFMA) ----------------
__global__ __launch_bounds__(256, 2)
void k_gemm(const unsigned short* __restrict__ wb, const unsigned short* __restrict__ xT,
            unsigned short* __restrict__ qkv){
  const int b  = blockIdx.z;
  const int m0 = blockIdx.y * 128;
  const int n0 = blockIdx.x * 128;
  __shared__ unsigned short As[128 * 64];
  __shared__ unsigned short Bs[128 * 64];
  const int t = threadIdx.x;
  const int lane = t & 63;
  const int w = t >> 6, wr = w >> 1, wc = w & 1;
  f32x4 acc[4][4];
#pragma unroll
  for (int i = 0; i < 4; ++i)
#pragma unroll
    for (int j = 0; j < 4; ++j) acc[i][j] = (f32x4){0.f,0.f,0.f,0.f};

  const unsigned short* Ag = wb + (size_t)m0 * DIM_;
  const unsigned short* Bg = xT + ((size_t)b * HW_ + n0) * DIM_;

  for (int k0 = 0; k0 < DIM_; k0 += 64){
#pragma unroll
    for (int i = 0; i < 4; ++i){
      const int q = i * 256 + t;
      const int qb = q & ~63;
      const int r = q >> 3, c = q & 7;
      __builtin_amdgcn_global_load_lds(
        (const __attribute__((address_space(1))) void*)(Ag + (size_t)r * DIM_ + k0 + c * 8),
        (__attribute__((address_space(3))) void*)(As + qb * 8), 16, 0, 0);
    }
#pragma unroll
    for (int i = 0; i < 4; ++i){
      const int q = i * 256 + t;
      const int qb = q & ~63;
      const int r = q >> 3, c = q & 7;
      __builtin_amdgcn_global_load_lds(
        (const __attribute__((address_space(1))) void*)(Bg + (size_t)r * DIM_ + k0 + c * 8),
        (__attribute__((address_space(3))) void*)(Bs + qb * 8), 16, 0, 0);
    }
    __syncthreads();
#pragma unroll
    for (int ks = 0; ks < 2; ++ks){
      const int kb = ks * 32 + (lane >> 4) * 8;
      bf16x8 af[4], bfr[4];
#pragma unroll
      for (int mi = 0; mi < 4; ++mi){
        const int row = wr * 64 + mi * 16 + (lane & 15);
        af[mi] = *reinterpret_cast<const bf16x8*>(As + row * 64 + kb);
      }
#pragma unroll
      for (int ni = 0; ni < 4; ++ni){
        const int row = wc * 64 + ni * 16 + (lane & 15);
        bfr[ni] = *reinterpret_cast<const bf16x8*>(Bs + row * 64 + kb);
      }
#pragma unroll
      for (int mi = 0; mi < 4; ++mi)
#pragma unroll
        for (int ni = 0; ni < 4; ++ni)
          acc[mi][ni] = __builtin_amdgcn_mfma_f32_16x16x32_bf16(af[mi], bfr[ni], acc[mi][ni], 0, 0, 0);
    }
    __syncthreads();
  }
  unsigned short* yb = qkv + ((size_t)b * CH3 + m0) * HW_ + n0;
#pragma unroll
  for (int mi = 0; mi < 4; ++mi){
    const int rbase = wr * 64 + mi * 16 + (lane >> 4) * 4;
#pragma unroll
    for (int ni = 0; ni < 4; ++ni){
      const int col = wc * 64 + ni * 16 + (lane & 15);
#pragma unroll
      for (int r = 0; r < 4; ++r)
        yb[(size_t)(rbase + r) * HW_ + col] = f2b(acc[mi][ni][r]);
    }
  }
}

// ---------------- K1: depthwise 3x3 in-place, global-direct (no LDS) ----------------
// Each thread: 16 px of one image row. Reads 3x18 bf16 neighborhood via aligned
// u16x8 loads (plane is L1-resident), accumulates in registads, barrier, write.
__global__ __launch_bounds__(256)
void k_dwconv(unsigned short* __restrict__ qkv, const float* __restrict__ w_dw){
  const int pc = blockIdx.x;               // b*1152 + ch
  const int ch = pc % CH3;
  unsigned short* plane = qkv + (size_t)pc * HW_;
  const int t  = threadIdx.x;
  const int y  = t >> 2;
  const int x0 = (t & 3) * 16;
  float w9[9];
#pragma unroll
  for (int i = 0; i < 9; ++i) w9[i] = w_dw[ch * 9 + i];
  float acc16[16];
#pragma unroll
  for (int j = 0; j < 16; ++j) acc16[j] = 0.f;
#pragma unroll
  for (int dy = -1; dy <= 1; ++dy){
    const int yy = y + dy;
    if ((unsigned)yy >= (unsigned)IMG) continue;
    const unsigned short* rp = plane + yy * IMG;
    u16x8 C0 = *reinterpret_cast<const u16x8*>(rp + x0);
    u16x8 C1 = *reinterpret_cast<const u16x8*>(rp + x0 + 8);
    float rw[18];
    rw[0]  = (x0 > 0)  ? b2f(rp[x0 - 1])  : 0.f;
    rw[17] = (x0 < 48) ? b2f(rp[x0 + 16]) : 0.f;
#pragma unroll
    for (int j = 0; j < 8; ++j){ rw[1+j] = b2f(C0[j]); rw[9+j] = b2f(C1[j]); }
    const float w0 = w9[(dy+1)*3], w1 = w9[(dy+1)*3+1], w2 = w9[(dy+1)*3+2];
#pragma unroll
    for (int j = 0; j < 16; ++j)
      acc16[j] = fmaf(rw[j], w0, fmaf(rw[j+1], w1, fmaf(rw[j+2], w2, acc16[j])));
  }
  __syncthreads();   // all reads of the original plane complete before any write
  u16x8 o0, o1;
#pragma unroll
  for (int j = 0; j < 8; ++j){ o0[j] = f2b(acc16[j]); o1[j] = f2b(acc16[8+j]); }
  *reinterpret_cast<u16x8*>(plane + (size_t)y * IMG + x0)     = o0;
  *reinterpret_cast<u16x8*>(plane + (size_t)y * IMG + x0 + 8) = o1;
}

// ---------------- K2: per (b,head,d) softmax params ----------------
__global__ __launch_bounds__(256)
void k_rowstats(const unsigned short* __restrict__ dqkv, const float* __restrict__ temperature,
                const float* __restrict__ w_ar, float* __restrict__ prm){
  const int bid  = blockIdx.x;             // b*384 + head*48 + d
  const int d    = bid % D_;
  const int head = (bid / D_) % HEADS_;
  const int b    = bid / (D_ * HEADS_);
  const int cq   = head * D_ + d;
  const unsigned short* qp = dqkv + ((size_t)b * CH3 + cq) * HW_;
  const unsigned short* kp = qp + (size_t)DIM_ * HW_;
  __shared__ float lds[8];
  const int t = threadIdx.x;
  float p[16];
  float sq = 0.f, sk = 0.f, pmx = -3.0e38f, pmn = 3.0e38f;
  {
    u16x8 q0 = *reinterpret_cast<const u16x8*>(qp + t * 16);
    u16x8 q1 = *reinterpret_cast<const u16x8*>(qp + t * 16 + 8);
    u16x8 k0 = *reinterpret_cast<const u16x8*>(kp + t * 16);
    u16x8 k1 = *reinterpret_cast<const u16x8*>(kp + t * 16 + 8);
#pragma unroll
    for (int j = 0; j < 8; ++j){
      float fq = b2f(q0[j]), fk = b2f(k0[j]);
      sq = fmaf(fq, fq, sq); sk = fmaf(fk, fk, sk);
      p[j] = fq * fk; pmx = fmaxf(pmx, p[j]); pmn = fminf(pmn, p[j]);
    }
#pragma unroll
    for (int j = 0; j < 8; ++j){
      float fq = b2f(q1[j]), fk = b2f(k1[j]);
      sq = fmaf(fq, fq, sq); sk = fmaf(fk, fk, sk);
      p[8+j] = fq * fk; pmx = fmaxf(pmx, p[8+j]); pmn = fminf(pmn, p[8+j]);
    }
  }
  sq  = block_red<0>(sq, lds);
  sk  = block_red<0>(sk, lds);
  pmx = block_red<1>(pmx, lds);
  pmn = block_red<2>(pmn, lds);
  const float nq = fmaxf(sqrtf(sq), 1e-12f);
  const float nk = fmaxf(sqrtf(sk), 1e-12f);
  const float c  = temperature[head] / (nq * nk);
  const float m  = (c >= 0.f) ? c * pmx : c * pmn;
  float se = 0.f;
#pragma unroll
  for (int j = 0; j < 16; ++j) se += expf(fmaf(c, p[j], -m));
  se = block_red<0>(se, lds);
  if (t == 0){
    prm[bid*3+0] = c;
    prm[bid*3+1] = m;
    prm[bid*3+2] = w_ar[d] / se;
  }
}

// ---------------- K3: a[n] = sum_d (w_ar[d]/se_d) * exp(c_d*p - m_d) ----------------
// grid (8, 64): 512 blocks, 2 px/thread, 4B coalesced loads
__global__ __launch_bounds__(256)
void k_attn_a(const unsigned short* __restrict__ dqkv, const float* __restrict__ prm,
              float* __restrict__ abuf){
  const int bh   = blockIdx.y;
  const int head = bh & 7, b = bh >> 3;
  const int t = threadIdx.x;
  const int px0 = (blockIdx.x * 256 + t) * 2;
  __shared__ float pc[D_ * 3];
  for (int i = t; i < D_ * 3; i += 256) pc[i] = prm[bh * (D_ * 3) + i];
  __syncthreads();
  const unsigned short* qb = dqkv + ((size_t)b * CH3 + head * D_) * HW_ + px0;
  const unsigned short* kb = qb + (size_t)DIM_ * HW_;
  float a0 = 0.f, a1 = 0.f;
  for (int d = 0; d < D_; ++d){
    const uint32_t qv = *reinterpret_cast<const uint32_t*>(qb + (size_t)d * HW_);
    const uint32_t kv = *reinterpret_cast<const uint32_t*>(kb + (size_t)d * HW_);
    const float cc = pc[d*3], mm = pc[d*3+1], ww = pc[d*3+2];
    const float p0 = b2f((unsigned short)qv) * b2f((unsigned short)kv);
    const float p1 = b2f((unsigned short)(qv >> 16)) * b2f((unsigned short)(kv >> 16));
    a0 = fmaf(ww, expf(fmaf(cc, p0, -mm)), a0);
    a1 = fmaf(ww, expf(fmaf(cc, p1, -mm)), a1);
  }
  float2 o; o.x = a0; o.y = a1;
  *reinterpret_cast<float2*>(abuf + (size_t)bh * HW_ + px0) = o;
}

// ---------------- K4: cmask = softmax_n(a) in place ----------------
__global__ __launch_bounds__(256)
void k_cmask(float* __restrict__ abuf){
  const int bh = blockIdx.x;
  float* a = abuf + (size_t)bh * HW_;
  __shared__ float lds[8];
  const int t = threadIdx.x;
  float va[16];
  float mx = -3.0e38f;
#pragma unroll
  for (int i = 0; i < 16; ++i){ va[i] = a[t + i*256]; mx = fmaxf(mx, va[i]); }
  mx = block_red<1>(mx, lds);
  float s = 0.f;
#pragma unroll
  for (int i = 0; i < 16; ++i){ va[i] = expf(va[i]-mx); s += va[i]; }
  s = block_red<0>(s, lds);
  const float inv = 1.f / s;
#pragma unroll
  for (int i = 0; i < 16; ++i) a[t + i*256] = va[i]*inv;
}

// ---------------- K5: vctx[b,head,d] = sum_n cmask[n]*dv[d,n] ----------------
__global__ __launch_bounds__(256)
void k_vctx(const unsigned short* __restrict__ dqkv, const float* __restrict__ abuf,
            float* __restrict__ vctx){
  const int bid  = blockIdx.x;
  const int d    = bid % D_;
  const int head = (bid / D_) % HEADS_;
  const int b    = bid / (D_ * HEADS_);
  const unsigned short* vp = dqkv + ((size_t)b * CH3 + 2*DIM_ + head*D_ + d) * HW_;
  const float* cm = abuf + ((size_t)(b * HEADS_ + head)) * HW_;
  __shared__ float lds[8];
  const int t = threadIdx.x;
  float s = 0.f;
  u16x8 v0 = *reinterpret_cast<const u16x8*>(vp + t * 16);
  u16x8 v1 = *reinterpret_cast<const u16x8*>(vp + t * 16 + 8);
#pragma unroll
  for (int j = 0; j < 8; ++j) s = fmaf(cm[t*16 + j],     b2f(v0[j]), s);
#pragma unroll
  for (int j = 0; j < 8; ++j) s = fmaf(cm[t*16 + 8 + j], b2f(v1[j]), s);
  s = block_red<0>(s, lds);
  if (t == 0) vctx[bid] = s;
}

// ---------------- K6: sp[b,h,n] = sigmoid(sum_d u[d]*dv[d,n]) ----------------
// grid (8, 64): 512 blocks, 2 px/thread
__global__ __launch_bounds__(256)
void k_spmask(const unsigned short* __restrict__ dqkv, const float* __restrict__ w_al,
              const float* __restrict__ w_vl, float* __restrict__ spb){
  const int bh   = blockIdx.y;
  const int head = bh & 7, b = bh >> 3;
  const int t = threadIdx.x;
  const int px0 = (blockIdx.x * 256 + t) * 2;
  __shared__ float u[D_];
  __shared__ float avg[DH_];
  if (t < DH_){
    float s = 0.f;
    for (int d = 0; d < D_; ++d) s += w_al[t*D_ + d];
    avg[t] = s * (1.f/(float)HW_);
  }
  __syncthreads();
  if (t == 0){
    float mx = avg[0];
    for (int o = 1; o < DH_; ++o) mx = fmaxf(mx, avg[o]);
    float s = 0.f;
    for (int o = 0; o < DH_; ++o){ avg[o] = expf(avg[o]-mx); s += avg[o]; }
    const float inv = 1.f/s;
    for (int o = 0; o < DH_; ++o) avg[o] *= inv;
  }
  __syncthreads();
  if (t < D_){
    float s = 0.f;
    for (int o = 0; o < DH_; ++o) s = fmaf(avg[o], w_vl[o*D_ + t], s);
    u[t] = s;
  }
  __syncthreads();
  const unsigned short* vb = dqkv + ((size_t)b * CH3 + 2*DIM_ + head*D_) * HW_ + px0;
  float a0 = 0.f, a1 = 0.f;
  for (int d = 0; d < D_; ++d){
    const uint32_t vv = *reinterpret_cast<const uint32_t*>(vb + (size_t)d * HW_);
    const float ud = u[d];
    a0 = fmaf(ud, b2f((unsigned short)vv), a0);
    a1 = fmaf(ud, b2f((unsigned short)(vv >> 16)), a1);
  }
  float2 o;
  o.x = 1.f/(1.f + expf(-a0));
  o.y = 1.f/(1.f + expf(-a1));
  *reinterpret_cast<float2*>(spb + (size_t)bh * HW_ + px0) = o;
}

// ---------------- K7: per-b MLP + LayerNorm -> mask_ch[b, c=d*8+head] ----------------
__global__ __launch_bounds__(256)
void k_maskch(const float* __restrict__ vctx, const float* __restrict__ w_vr,
              const float* __restrict__ w_up1, const float* __restrict__ b_up1,
              const float* __restrict__ ln_g, const float* __restrict__ ln_b,
              const float* __restrict__ w_up2, const float* __restrict__ b_up2,
              float* __restrict__ mch){
  const int b = blockIdx.x;
  const int t = threadIdx.x;
  __shared__ float vc[HEADS_*D_];
  __shared__ float cx[HEADS_*DH_];
  __shared__ float t1[D2_*HEADS_];
  __shared__ float lds[8];
  for (int i = t; i < HEADS_*D_; i += 256) vc[i] = vctx[b*HEADS_*D_ + i];
  __syncthreads();
  if (t < HEADS_*DH_){
    const int head = t / DH_, o = t % DH_;
    float s = 0.f;
    for (int d = 0; d < D_; ++d) s = fmaf(w_vr[o*D_+d], vc[head*D_+d], s);
    cx[head*DH_+o] = s;
  }
  __syncthreads();
  const int o2 = t >> 3, hh = t & 7;
  float val = b_up1[o2];
  for (int o = 0; o < DH_; ++o) val = fmaf(w_up1[o2*DH_+o], cx[hh*DH_+o], val);
  const float mu  = block_red<0>(val, lds) * (1.f/256.f);
  const float dv  = val - mu;
  const float var = block_red<0>(dv*dv, lds) * (1.f/256.f);
  float yv = dv / sqrtf(var + 1e-5f);
  yv = fmaf(yv, ln_g[t], ln_b[t]);
  yv = fmaxf(yv, 0.f);
  t1[t] = yv;
  __syncthreads();
  for (int idx = t; idx < D_*HEADS_; idx += 256){
    const int d = idx >> 3, head2 = idx & 7;
    float s = b_up2[d];
    for (int o = 0; o < D2_; ++o) s = fmaf(w_up2[d*D2_+o], t1[o*HEADS_+head2], s);
    mch[b*DIM_ + idx] = 1.f/(1.f + expf(-s));
  }
}

// ---------------- K8: out = x * (mask_ch + sum_h w_proj*sp) ----------------
__global__ __launch_bounds__(256)
void k_out(const float* __restrict__ x, const float* __restrict__ spb,
           const float* __restrict__ mch, const float* __restrict__ w_proj,
           float* __restrict__ out){
  const int b  = blockIdx.z;
  const int c0 = blockIdx.y * 16;
  const int n  = blockIdx.x * 1024 + threadIdx.x * 4;
  float4 sv[8];
#pragma unroll
  for (int h = 0; h < 8; ++h)
    sv[h] = *reinterpret_cast<const float4*>(spb + ((size_t)(b*8+h))*HW_ + n);
  for (int ci = 0; ci < 16; ++ci){
    const int c = c0 + ci;
    const float g = mch[b*DIM_ + c];
    float4 gv; gv.x = g; gv.y = g; gv.z = g; gv.w = g;
#pragma unroll
    for (int h = 0; h < 8; ++h){
      const float wp = w_proj[c*8+h];
      gv.x = fmaf(wp, sv[h].x, gv.x); gv.y = fmaf(wp, sv[h].y, gv.y);
      gv.z = fmaf(wp, sv[h].z, gv.z); gv.w = fmaf(wp, sv[h].w, gv.w);
    }
    const size_t off = ((size_t)b*DIM_ + c)*HW_ + n;
    float4 xv = *reinterpret_cast<const float4*>(x + off);
    xv.x *= gv.x; xv.y *= gv.y; xv.z *= gv.z; xv.w *= gv.w;
    *reinterpret_cast<float4*>(out + off) = xv;
  }
}

extern "C" void kernel_launch(void* const* d_in, const int* in_sizes, int n_in,
                              void* d_out, int out_size, void* d_ws, size_t ws_size,
                              hipStream_t stream) {
  const float* x      = (const float*)d_in[0];
  const float* w_qkv  = (const float*)d_in[1];
  const float* w_dw   = (const float*)d_in[2];
  const float* temp   = (const float*)d_in[3];
  const float* w_ar   = (const float*)d_in[4];
  const float* w_vr   = (const float*)d_in[5];
  const float* w_up1  = (const float*)d_in[6];
  const float* b_up1  = (const float*)d_in[7];
  const float* ln_g   = (const float*)d_in[8];
  const float* ln_b   = (const float*)d_in[9];
  const float* w_up2  = (const float*)d_in[10];
  const float* b_up2  = (const float*)d_in[11];
  const float* w_al   = (const float*)d_in[12];
  const float* w_vl   = (const float*)d_in[13];
  const float* w_proj = (const float*)d_in[14];
  float* out = (float*)d_out;

  unsigned short* qkvb = (unsigned short*)d_ws;              // 8*1152*4096 bf16
  unsigned short* xT   = qkvb + (size_t)B_*CH3*HW_;          // 8*4096*384 bf16
  unsigned short* wb   = xT + (size_t)B_*HW_*DIM_;           // 1152*384 bf16
  float* prm  = (float*)(wb + (size_t)CH3*DIM_);             // 3072*3
  float* abuf = prm + 3*B_*HEADS_*D_;                        // 64*4096
  float* vctx = abuf + (size_t)B_*HEADS_*HW_;                // 3072
  float* spb  = vctx + B_*HEADS_*D_;                         // 64*4096
  float* mch  = spb + (size_t)B_*HEADS_*HW_;                 // 8*384

  k_cvtw<<<dim3((CH3*DIM_)/1024), 256, 0, stream>>>(w_qkv, wb);
  k_prep<<<dim3(HW_/64, DIM_/64, B_), 256, 0, stream>>>(x, xT);
  k_gemm<<<dim3(HW_/128, CH3/128, B_), 256, 0, stream>>>(wb, xT, qkvb);
  k_dwconv<<<dim3(B_*CH3), 256, 0, stream>>>(qkvb, w_dw);
  k_rowstats<<<dim3(B_*HEADS_*D_), 256, 0, stream>>>(qkvb, temp, w_ar, prm);
  k_attn_a<<<dim3(8, B_*HEADS_), 256, 0, stream>>>(qkvb, prm, abuf);
  k_cmask<<<dim3(B_*HEADS_), 256, 0, stream>>>(abuf);
  k_vctx<<<dim3(B_*HEADS_*D_), 256, 0, stream>>>(qkvb, abuf, vctx);
  k_spmask<<<dim3(8, B_*HEADS_), 256, 0, stream>>>(qkvb, w_al, w_vl, spb);
  k_maskch<<<dim3(B_), 256, 0, stream>>>(vctx, w_vr, w_up1, b_up1, ln_g, ln_b,
                                         w_up2, b_up2, mch);
  k_out<<<dim3(HW_/1024, DIM_/16, B_), 256, 0, stream>>>(x, spb, mch, w_proj, out);
}

// Round 5
// 262.518 us; speedup vs baseline: 4.2518x; 1.0109x over previous
//
#include <hip/hip_runtime.h>
#include <math.h>
#include <stdint.h>

#define B_     8
#define DIM_   384
#define HEADS_ 8
#define D_     48
#define DH_    24
#define D2_    32
#define HW_    4096
#define IMG    64
#define CH3    1152   // 3*DIM

typedef __attribute__((ext_vector_type(8))) __bf16   bf16x8;
typedef __attribute__((ext_vector_type(4))) float    f32x4;
typedef __attribute__((ext_vector_type(8))) unsigned short u16x8;

__device__ __forceinline__ float b2f(unsigned short h){
  union { uint32_t u; float f; } v; v.u = ((uint32_t)h) << 16; return v.f;
}
__device__ __forceinline__ unsigned short f2b(float f){
  union { float f; uint32_t u; } v; v.f = f;
  uint32_t r = v.u + 0x7fffu + ((v.u >> 16) & 1u);   // RNE
  return (unsigned short)(r >> 16);
}

// ---------------- reduction helpers ----------------
__device__ __forceinline__ float wred_sum(float v){
#pragma unroll
  for (int m = 32; m; m >>= 1) v += __shfl_xor(v, m);
  return v;
}
__device__ __forceinline__ float wred_max(float v){
#pragma unroll
  for (int m = 32; m; m >>= 1) v = fmaxf(v, __shfl_xor(v, m));
  return v;
}
__device__ __forceinline__ float wred_min(float v){
#pragma unroll
  for (int m = 32; m; m >>= 1) v = fminf(v, __shfl_xor(v, m));
  return v;
}
template<int OP>  // 0=sum 1=max 2=min
__device__ __forceinline__ float block_red(float v, float* lds){
  if (OP == 0) v = wred_sum(v);
  else if (OP == 1) v = wred_max(v);
  else v = wred_min(v);
  const int lane = threadIdx.x & 63;
  const int wid  = threadIdx.x >> 6;
  __syncthreads();
  if (lane == 0) lds[wid] = v;
  __syncthreads();
  const int nw = blockDim.x >> 6;
  float r = lds[0];
  for (int i = 1; i < nw; ++i){
    float o = lds[i];
    if (OP == 0) r += o; else if (OP == 1) r = fmaxf(r, o); else r = fminf(r, o);
  }
  return r;
}

// depthwise 3x3 over 16 px of one image row, reading bf16 plane directly
__device__ __forceinline__ void dwplane16(const unsigned short* __restrict__ plane,
                                          const float* w9, int y, int x0, float* acc16){
#pragma unroll
  for (int j = 0; j < 16; ++j) acc16[j] = 0.f;
#pragma unroll
  for (int dy = -1; dy <= 1; ++dy){
    const int yy = y + dy;
    if ((unsigned)yy >= (unsigned)IMG) continue;
    const unsigned short* rp = plane + yy * IMG;
    u16x8 C0 = *reinterpret_cast<const u16x8*>(rp + x0);
    u16x8 C1 = *reinterpret_cast<const u16x8*>(rp + x0 + 8);
    float rw[18];
    rw[0]  = (x0 > 0)  ? b2f(rp[x0 - 1])  : 0.f;
    rw[17] = (x0 < 48) ? b2f(rp[x0 + 16]) : 0.f;
#pragma unroll
    for (int j = 0; j < 8; ++j){ rw[1+j] = b2f(C0[j]); rw[9+j] = b2f(C1[j]); }
    const float w0 = w9[(dy+1)*3], w1 = w9[(dy+1)*3+1], w2 = w9[(dy+1)*3+2];
#pragma unroll
    for (int j = 0; j < 16; ++j)
      acc16[j] = fmaf(rw[j], w0, fmaf(rw[j+1], w1, fmaf(rw[j+2], w2, acc16[j])));
  }
}

// ---------------- P0a: w_qkv -> bf16 ----------------
__global__ __launch_bounds__(256)
void k_cvtw(const float* __restrict__ w, unsigned short* __restrict__ wb){
  const int i = (blockIdx.x * 256 + threadIdx.x) * 4;
  float4 v = *reinterpret_cast<const float4*>(w + i);
  wb[i+0] = f2b(v.x); wb[i+1] = f2b(v.y); wb[i+2] = f2b(v.z); wb[i+3] = f2b(v.w);
}

// ---------------- P0b: x [b,384,4096] f32 -> xT [b,4096,384] bf16 ----------------
__global__ __launch_bounds__(256)
void k_prep(const float* __restrict__ x, unsigned short* __restrict__ xT){
  __shared__ unsigned short Ts[64][66];
  const int t = threadIdx.x;
  const float* xb = x + ((size_t)blockIdx.z * DIM_ + blockIdx.y * 64) * HW_ + blockIdx.x * 64;
#pragma unroll
  for (int rr = 0; rr < 4; ++rr){
    const int r = (t >> 4) + rr * 16;
    const int c = (t & 15) * 4;
    float4 v = *reinterpret_cast<const float4*>(xb + (size_t)r * HW_ + c);
    Ts[r][c+0] = f2b(v.x); Ts[r][c+1] = f2b(v.y); Ts[r][c+2] = f2b(v.z); Ts[r][c+3] = f2b(v.w);
  }
  __syncthreads();
  const int rn = t >> 2, kc = (t & 3) * 16;
  unsigned short* yb = xT + ((size_t)blockIdx.z * HW_ + blockIdx.x * 64 + rn) * DIM_
                          + blockIdx.y * 64 + kc;
  u16x8 o0, o1;
#pragma unroll
  for (int j = 0; j < 8; ++j){ o0[j] = Ts[kc + j][rn]; o1[j] = Ts[kc + 8 + j][rn]; }
  *reinterpret_cast<u16x8*>(yb)     = o0;
  *reinterpret_cast<u16x8*>(yb + 8) = o1;
}

// ---------------- K0: qkv[b,m,n] = sum_k wb[m,k]*xT[b,n,k]  (bf16 MFMA) ----------------
// 128x128 tile, BK=64, double-buffered LDS, counted vmcnt + raw barriers,
// both-sides XOR chunk swizzle (LDS dest linear; source + ds_read swizzled).
__global__ __launch_bounds__(256)
void k_gemm(const unsigned short* __restrict__ wb, const unsigned short* __restrict__ xT,
            unsigned short* __restrict__ qkv){
  const int b  = blockIdx.z;
  const int m0 = blockIdx.y * 128;
  const int n0 = blockIdx.x * 128;
  __shared__ unsigned short As[2][128 * 64];
  __shared__ unsigned short Bs[2][128 * 64];
  const int t = threadIdx.x;
  const int lane = t & 63;
  const int fr = lane & 15;          // fragment row-in-16
  const int ld = lane >> 4;          // 0..3 k-subchunk
  const int w = t >> 6, wr = w >> 1, wc = w & 1;
  f32x4 acc[4][4];
#pragma unroll
  for (int i = 0; i < 4; ++i)
#pragma unroll
    for (int j = 0; j < 4; ++j) acc[i][j] = (f32x4){0.f,0.f,0.f,0.f};

  const unsigned short* Ag = wb + (size_t)m0 * DIM_;
  const unsigned short* Bg = xT + ((size_t)b * HW_ + n0) * DIM_;

  auto stage = [&](int buf, int k0){
#pragma unroll
    for (int i = 0; i < 4; ++i){
      const int q = i * 256 + t;
      const int qb = q & ~63;             // wave-uniform base chunk
      const int r = q >> 3, c = q & 7;
      const int cs = c ^ (r & 7);         // pre-swizzled global source
      __builtin_amdgcn_global_load_lds(
        (const __attribute__((address_space(1))) void*)(Ag + (size_t)r * DIM_ + k0 + cs * 8),
        (__attribute__((address_space(3))) void*)(&As[buf][qb * 8]), 16, 0, 0);
    }
#pragma unroll
    for (int i = 0; i < 4; ++i){
      const int q = i * 256 + t;
      const int qb = q & ~63;
      const int r = q >> 3, c = q & 7;
      const int cs = c ^ (r & 7);
      __builtin_amdgcn_global_load_lds(
        (const __attribute__((address_space(1))) void*)(Bg + (size_t)r * DIM_ + k0 + cs * 8),
        (__attribute__((address_space(3))) void*)(&Bs[buf][qb * 8]), 16, 0, 0);
    }
  };

  stage(0, 0);
  for (int it = 0; it < 6; ++it){
    const int cur = it & 1;
    if (it < 5){
      stage(cur ^ 1, (it + 1) * 64);
      asm volatile("s_waitcnt vmcnt(8)" ::: "memory");   // wait stage(it); keep next 8 in flight
    } else {
      asm volatile("s_waitcnt vmcnt(0)" ::: "memory");
    }
    __builtin_amdgcn_s_barrier();
    asm volatile("" ::: "memory");
#pragma unroll
    for (int ks = 0; ks < 2; ++ks){
      bf16x8 af[4], bfr[4];
#pragma unroll
      for (int mi = 0; mi < 4; ++mi){
        const int row = wr * 64 + mi * 16 + fr;
        const int cc = (ks * 4 + ld) ^ (row & 7);        // swizzled read
        af[mi] = *reinterpret_cast<const bf16x8*>(&As[cur][row * 64 + cc * 8]);
      }
#pragma unroll
      for (int ni = 0; ni < 4; ++ni){
        const int row = wc * 64 + ni * 16 + fr;
        const int cc = (ks * 4 + ld) ^ (row & 7);
        bfr[ni] = *reinterpret_cast<const bf16x8*>(&Bs[cur][row * 64 + cc * 8]);
      }
#pragma unroll
      for (int mi = 0; mi < 4; ++mi)
#pragma unroll
        for (int ni = 0; ni < 4; ++ni)
          acc[mi][ni] = __builtin_amdgcn_mfma_f32_16x16x32_bf16(af[mi], bfr[ni], acc[mi][ni], 0, 0, 0);
    }
    asm volatile("" ::: "memory");
    __builtin_amdgcn_s_barrier();
  }
  unsigned short* yb = qkv + ((size_t)b * CH3 + m0) * HW_ + n0;
#pragma unroll
  for (int mi = 0; mi < 4; ++mi){
    const int rbase = wr * 64 + mi * 16 + (lane >> 4) * 4;
#pragma unroll
    for (int ni = 0; ni < 4; ++ni){
      const int col = wc * 64 + ni * 16 + (lane & 15);
#pragma unroll
      for (int r = 0; r < 4; ++r)
        yb[(size_t)(rbase + r) * HW_ + col] = f2b(acc[mi][ni][r]);
    }
  }
}

// ---------------- K1a: dwconv q+k pair, in-place, fused rowstats ----------------
// One block per (b, ch): conv both q and k planes, round to bf16, compute
// softmax params from the ROUNDED values (bit-identical to k_attn_a's reload).
__global__ __launch_bounds__(256)
void k_dwqk(unsigned short* __restrict__ qkv, const float* __restrict__ w_dw,
            const float* __restrict__ temperature, const float* __restrict__ w_ar,
            float* __restrict__ prm){
  const int pc = blockIdx.x;               // b*384 + ch
  const int ch = pc % DIM_;
  const int b  = pc / DIM_;
  const int d  = ch % D_;
  const int head = ch / D_;
  unsigned short* qp = qkv + ((size_t)b * CH3 + ch) * HW_;
  unsigned short* kp = qp + (size_t)DIM_ * HW_;
  const int t  = threadIdx.x;
  const int y  = t >> 2;
  const int x0 = (t & 3) * 16;
  float wq9[9], wk9[9];
#pragma unroll
  for (int i = 0; i < 9; ++i){ wq9[i] = w_dw[ch*9+i]; wk9[i] = w_dw[(DIM_+ch)*9+i]; }
  float aq[16], ak[16];
  dwplane16(qp, wq9, y, x0, aq);
  dwplane16(kp, wk9, y, x0, ak);
  unsigned short qs[16], kss[16];
#pragma unroll
  for (int j = 0; j < 16; ++j){ qs[j] = f2b(aq[j]); kss[j] = f2b(ak[j]); }
  // stats from rounded values (consistent with attn_a)
  __shared__ float lds[8];
  float p[16];
  float sq = 0.f, sk = 0.f, pmx = -3.0e38f, pmn = 3.0e38f;
#pragma unroll
  for (int j = 0; j < 16; ++j){
    const float fq = b2f(qs[j]), fk = b2f(kss[j]);
    sq = fmaf(fq, fq, sq); sk = fmaf(fk, fk, sk);
    p[j] = fq * fk; pmx = fmaxf(pmx, p[j]); pmn = fminf(pmn, p[j]);
  }
  sq  = block_red<0>(sq, lds);
  sk  = block_red<0>(sk, lds);
  pmx = block_red<1>(pmx, lds);
  pmn = block_red<2>(pmn, lds);
  const float nq = fmaxf(sqrtf(sq), 1e-12f);
  const float nk = fmaxf(sqrtf(sk), 1e-12f);
  const float c  = temperature[head] / (nq * nk);
  const float m  = (c >= 0.f) ? c * pmx : c * pmn;
  float se = 0.f;
#pragma unroll
  for (int j = 0; j < 16; ++j) se += expf(fmaf(c, p[j], -m));
  se = block_red<0>(se, lds);
  // block_red's syncthreads ensure all neighborhood reads done -> safe in-place write
  u16x8 o0, o1;
#pragma unroll
  for (int j = 0; j < 8; ++j){ o0[j] = qs[j]; o1[j] = qs[8+j]; }
  *reinterpret_cast<u16x8*>(qp + (size_t)y * IMG + x0)     = o0;
  *reinterpret_cast<u16x8*>(qp + (size_t)y * IMG + x0 + 8) = o1;
#pragma unroll
  for (int j = 0; j < 8; ++j){ o0[j] = kss[j]; o1[j] = kss[8+j]; }
  *reinterpret_cast<u16x8*>(kp + (size_t)y * IMG + x0)     = o0;
  *reinterpret_cast<u16x8*>(kp + (size_t)y * IMG + x0 + 8) = o1;
  if (t == 0){
    prm[pc*3+0] = c;
    prm[pc*3+1] = m;
    prm[pc*3+2] = w_ar[d] / se;
  }
}

// ---------------- K1b: dwconv v planes, in-place ----------------
__global__ __launch_bounds__(256)
void k_dwv(unsigned short* __restrict__ qkv, const float* __restrict__ w_dw){
  const int pc = blockIdx.x;               // b*384 + ch
  const int ch = pc % DIM_;
  const int b  = pc / DIM_;
  const int cv = 2*DIM_ + ch;
  unsigned short* plane = qkv + ((size_t)b * CH3 + cv) * HW_;
  const int t  = threadIdx.x;
  const int y  = t >> 2;
  const int x0 = (t & 3) * 16;
  float w9[9];
#pragma unroll
  for (int i = 0; i < 9; ++i) w9[i] = w_dw[cv*9+i];
  float acc16[16];
  dwplane16(plane, w9, y, x0, acc16);
  __syncthreads();
  u16x8 o0, o1;
#pragma unroll
  for (int j = 0; j < 8; ++j){ o0[j] = f2b(acc16[j]); o1[j] = f2b(acc16[8+j]); }
  *reinterpret_cast<u16x8*>(plane + (size_t)y * IMG + x0)     = o0;
  *reinterpret_cast<u16x8*>(plane + (size_t)y * IMG + x0 + 8) = o1;
}

// ---------------- K3: a[n] = sum_d (w_ar[d]/se_d) * exp(c_d*p - m_d) ----------------
__global__ __launch_bounds__(256)
void k_attn_a(const unsigned short* __restrict__ dqkv, const float* __restrict__ prm,
              float* __restrict__ abuf){
  const int bh   = blockIdx.y;
  const int head = bh & 7, b = bh >> 3;
  const int t = threadIdx.x;
  const int px0 = (blockIdx.x * 256 + t) * 2;
  __shared__ float pc[D_ * 3];
  for (int i = t; i < D_ * 3; i += 256) pc[i] = prm[bh * (D_ * 3) + i];
  __syncthreads();
  const unsigned short* qb = dqkv + ((size_t)b * CH3 + head * D_) * HW_ + px0;
  const unsigned short* kb = qb + (size_t)DIM_ * HW_;
  float a0 = 0.f, a1 = 0.f;
  for (int d = 0; d < D_; ++d){
    const uint32_t qv = *reinterpret_cast<const uint32_t*>(qb + (size_t)d * HW_);
    const uint32_t kv = *reinterpret_cast<const uint32_t*>(kb + (size_t)d * HW_);
    const float cc = pc[d*3], mm = pc[d*3+1], ww = pc[d*3+2];
    const float p0 = b2f((unsigned short)qv) * b2f((unsigned short)kv);
    const float p1 = b2f((unsigned short)(qv >> 16)) * b2f((unsigned short)(kv >> 16));
    a0 = fmaf(ww, expf(fmaf(cc, p0, -mm)), a0);
    a1 = fmaf(ww, expf(fmaf(cc, p1, -mm)), a1);
  }
  float2 o; o.x = a0; o.y = a1;
  *reinterpret_cast<float2*>(abuf + (size_t)bh * HW_ + px0) = o;
}

// ---------------- K4: cmask = softmax_n(a) in place ----------------
__global__ __launch_bounds__(256)
void k_cmask(float* __restrict__ abuf){
  const int bh = blockIdx.x;
  float* a = abuf + (size_t)bh * HW_;
  __shared__ float lds[8];
  const int t = threadIdx.x;
  float va[16];
  float mx = -3.0e38f;
#pragma unroll
  for (int i = 0; i < 16; ++i){ va[i] = a[t + i*256]; mx = fmaxf(mx, va[i]); }
  mx = block_red<1>(mx, lds);
  float s = 0.f;
#pragma unroll
  for (int i = 0; i < 16; ++i){ va[i] = expf(va[i]-mx); s += va[i]; }
  s = block_red<0>(s, lds);
  const float inv = 1.f / s;
#pragma unroll
  for (int i = 0; i < 16; ++i) a[t + i*256] = va[i]*inv;
}

// ---------------- K5: vctx[b,head,d] = sum_n cmask[n]*dv[d,n] ----------------
__global__ __launch_bounds__(256)
void k_vctx(const unsigned short* __restrict__ dqkv, const float* __restrict__ abuf,
            float* __restrict__ vctx){
  const int bid  = blockIdx.x;
  const int d    = bid % D_;
  const int head = (bid / D_) % HEADS_;
  const int b    = bid / (D_ * HEADS_);
  const unsigned short* vp = dqkv + ((size_t)b * CH3 + 2*DIM_ + head*D_ + d) * HW_;
  const float* cm = abuf + ((size_t)(b * HEADS_ + head)) * HW_;
  __shared__ float lds[8];
  const int t = threadIdx.x;
  float s = 0.f;
  u16x8 v0 = *reinterpret_cast<const u16x8*>(vp + t * 16);
  u16x8 v1 = *reinterpret_cast<const u16x8*>(vp + t * 16 + 8);
#pragma unroll
  for (int j = 0; j < 8; ++j) s = fmaf(cm[t*16 + j],     b2f(v0[j]), s);
#pragma unroll
  for (int j = 0; j < 8; ++j) s = fmaf(cm[t*16 + 8 + j], b2f(v1[j]), s);
  s = block_red<0>(s, lds);
  if (t == 0) vctx[bid] = s;
}

// ---------------- K6: sp[b,h,n] = sigmoid(sum_d u[d]*dv[d,n]) ----------------
__global__ __launch_bounds__(256)
void k_spmask(const unsigned short* __restrict__ dqkv, const float* __restrict__ w_al,
              const float* __restrict__ w_vl, float* __restrict__ spb){
  const int bh   = blockIdx.y;
  const int head = bh & 7, b = bh >> 3;
  const int t = threadIdx.x;
  const int px0 = (blockIdx.x * 256 + t) * 2;
  __shared__ float u[D_];
  __shared__ float avg[DH_];
  if (t < DH_){
    float s = 0.f;
    for (int d = 0; d < D_; ++d) s += w_al[t*D_ + d];
    avg[t] = s * (1.f/(float)HW_);
  }
  __syncthreads();
  if (t == 0){
    float mx = avg[0];
    for (int o = 1; o < DH_; ++o) mx = fmaxf(mx, avg[o]);
    float s = 0.f;
    for (int o = 0; o < DH_; ++o){ avg[o] = expf(avg[o]-mx); s += avg[o]; }
    const float inv = 1.f/s;
    for (int o = 0; o < DH_; ++o) avg[o] *= inv;
  }
  __syncthreads();
  if (t < D_){
    float s = 0.f;
    for (int o = 0; o < DH_; ++o) s = fmaf(avg[o], w_vl[o*D_ + t], s);
    u[t] = s;
  }
  __syncthreads();
  const unsigned short* vb = dqkv + ((size_t)b * CH3 + 2*DIM_ + head*D_) * HW_ + px0;
  float a0 = 0.f, a1 = 0.f;
  for (int d = 0; d < D_; ++d){
    const uint32_t vv = *reinterpret_cast<const uint32_t*>(vb + (size_t)d * HW_);
    const float ud = u[d];
    a0 = fmaf(ud, b2f((unsigned short)vv), a0);
    a1 = fmaf(ud, b2f((unsigned short)(vv >> 16)), a1);
  }
  float2 o;
  o.x = 1.f/(1.f + expf(-a0));
  o.y = 1.f/(1.f + expf(-a1));
  *reinterpret_cast<float2*>(spb + (size_t)bh * HW_ + px0) = o;
}

// ---------------- K7: per-b MLP + LayerNorm -> mask_ch[b, c=d*8+head] ----------------
__global__ __launch_bounds__(256)
void k_maskch(const float* __restrict__ vctx, const float* __restrict__ w_vr,
              const float* __restrict__ w_up1, const float* __restrict__ b_up1,
              const float* __restrict__ ln_g, const float* __restrict__ ln_b,
              const float* __restrict__ w_up2, const float* __restrict__ b_up2,
              float* __restrict__ mch){
  const int b = blockIdx.x;
  const int t = threadIdx.x;
  __shared__ float vc[HEADS_*D_];
  __shared__ float cx[HEADS_*DH_];
  __shared__ float t1[D2_*HEADS_];
  __shared__ float lds[8];
  for (int i = t; i < HEADS_*D_; i += 256) vc[i] = vctx[b*HEADS_*D_ + i];
  __syncthreads();
  if (t < HEADS_*DH_){
    const int head = t / DH_, o = t % DH_;
    float s = 0.f;
    for (int d = 0; d < D_; ++d) s = fmaf(w_vr[o*D_+d], vc[head*D_+d], s);
    cx[head*DH_+o] = s;
  }
  __syncthreads();
  const int o2 = t >> 3, hh = t & 7;
  float val = b_up1[o2];
  for (int o = 0; o < DH_; ++o) val = fmaf(w_up1[o2*DH_+o], cx[hh*DH_+o], val);
  const float mu  = block_red<0>(val, lds) * (1.f/256.f);
  const float dv  = val - mu;
  const float var = block_red<0>(dv*dv, lds) * (1.f/256.f);
  float yv = dv / sqrtf(var + 1e-5f);
  yv = fmaf(yv, ln_g[t], ln_b[t]);
  yv = fmaxf(yv, 0.f);
  t1[t] = yv;
  __syncthreads();
  for (int idx = t; idx < D_*HEADS_; idx += 256){
    const int d = idx >> 3, head2 = idx & 7;
    float s = b_up2[d];
    for (int o = 0; o < D2_; ++o) s = fmaf(w_up2[d*D2_+o], t1[o*HEADS_+head2], s);
    mch[b*DIM_ + idx] = 1.f/(1.f + expf(-s));
  }
}

// ---------------- K8: out = x * (mask_ch + sum_h w_proj*sp) ----------------
__global__ __launch_bounds__(256)
void k_out(const float* __restrict__ x, const float* __restrict__ spb,
           const float* __restrict__ mch, const float* __restrict__ w_proj,
           float* __restrict__ out){
  const int b  = blockIdx.z;
  const int c0 = blockIdx.y * 16;
  const int n  = blockIdx.x * 1024 + threadIdx.x * 4;
  float4 sv[8];
#pragma unroll
  for (int h = 0; h < 8; ++h)
    sv[h] = *reinterpret_cast<const float4*>(spb + ((size_t)(b*8+h))*HW_ + n);
  for (int ci = 0; ci < 16; ++ci){
    const int c = c0 + ci;
    const float g = mch[b*DIM_ + c];
    float4 gv; gv.x = g; gv.y = g; gv.z = g; gv.w = g;
#pragma unroll
    for (int h = 0; h < 8; ++h){
      const float wp = w_proj[c*8+h];
      gv.x = fmaf(wp, sv[h].x, gv.x); gv.y = fmaf(wp, sv[h].y, gv.y);
      gv.z = fmaf(wp, sv[h].z, gv.z); gv.w = fmaf(wp, sv[h].w, gv.w);
    }
    const size_t off = ((size_t)b*DIM_ + c)*HW_ + n;
    float4 xv = *reinterpret_cast<const float4*>(x + off);
    xv.x *= gv.x; xv.y *= gv.y; xv.z *= gv.z; xv.w *= gv.w;
    *reinterpret_cast<float4*>(out + off) = xv;
  }
}

extern "C" void kernel_launch(void* const* d_in, const int* in_sizes, int n_in,
                              void* d_out, int out_size, void* d_ws, size_t ws_size,
                              hipStream_t stream) {
  const float* x      = (const float*)d_in[0];
  const float* w_qkv  = (const float*)d_in[1];
  const float* w_dw   = (const float*)d_in[2];
  const float* temp   = (const float*)d_in[3];
  const float* w_ar   = (const float*)d_in[4];
  const float* w_vr   = (const float*)d_in[5];
  const float* w_up1  = (const float*)d_in[6];
  const float* b_up1  = (const float*)d_in[7];
  const float* ln_g   = (const float*)d_in[8];
  const float* ln_b   = (const float*)d_in[9];
  const float* w_up2  = (const float*)d_in[10];
  const float* b_up2  = (const float*)d_in[11];
  const float* w_al   = (const float*)d_in[12];
  const float* w_vl   = (const float*)d_in[13];
  const float* w_proj = (const float*)d_in[14];
  float* out = (float*)d_out;

  unsigned short* qkvb = (unsigned short*)d_ws;              // 8*1152*4096 bf16
  unsigned short* xT   = qkvb + (size_t)B_*CH3*HW_;          // 8*4096*384 bf16
  unsigned short* wb   = xT + (size_t)B_*HW_*DIM_;           // 1152*384 bf16
  float* prm  = (float*)(wb + (size_t)CH3*DIM_);             // 3072*3
  float* abuf = prm + 3*B_*HEADS_*D_;                        // 64*4096
  float* vctx = abuf + (size_t)B_*HEADS_*HW_;                // 3072
  float* spb  = vctx + B_*HEADS_*D_;                         // 64*4096
  float* mch  = spb + (size_t)B_*HEADS_*HW_;                 // 8*384

  k_cvtw<<<dim3((CH3*DIM_)/1024), 256, 0, stream>>>(w_qkv, wb);
  k_prep<<<dim3(HW_/64, DIM_/64, B_), 256, 0, stream>>>(x, xT);
  k_gemm<<<dim3(HW_/128, CH3/128, B_), 256, 0, stream>>>(wb, xT, qkvb);
  k_dwqk<<<dim3(B_*DIM_), 256, 0, stream>>>(qkvb, w_dw, temp, w_ar, prm);
  k_dwv<<<dim3(B_*DIM_), 256, 0, stream>>>(qkvb, w_dw);
  k_attn_a<<<dim3(8, B_*HEADS_), 256, 0, stream>>>(qkvb, prm, abuf);
  k_cmask<<<dim3(B_*HEADS_), 256, 0, stream>>>(abuf);
  k_vctx<<<dim3(B_*HEADS_*D_), 256, 0, stream>>>(qkvb, abuf, vctx);
  k_spmask<<<dim3(8, B_*HEADS_), 256, 0, stream>>>(qkvb, w_al, w_vl, spb);
  k_maskch<<<dim3(B_), 256, 0, stream>>>(vctx, w_vr, w_up1, b_up1, ln_g, ln_b,
                                         w_up2, b_up2, mch);
  k_out<<<dim3(HW_/1024, DIM_/16, B_), 256, 0, stream>>>(x, spb, mch, w_proj, out);
}